// Round 1
// baseline (1036.864 us; speedup 1.0000x reference)
//
#include <hip/hip_runtime.h>
#include <math.h>

#define H 512
typedef unsigned short u16;
typedef __attribute__((ext_vector_type(8))) short bf16x8;
typedef __attribute__((ext_vector_type(4))) float f32x4;

constexpr int LEAF0  = 21845;   // starts[8]
constexpr int NLEAF  = 65536;
constexpr int NNODES = 87381;

__device__ __forceinline__ u16 f2b(float f) {
    union { float f; unsigned u; } v; v.f = f;
    unsigned r = v.u + 0x7fffu + ((v.u >> 16) & 1u);  // RNE
    return (u16)(r >> 16);
}
__device__ __forceinline__ float b2f(u16 b) {
    union { unsigned u; float f; } v; v.u = ((unsigned)b) << 16; return v.f;
}
__device__ __forceinline__ float sigm(float x) {
    return __fdividef(1.f, 1.f + __expf(-x));
}
__device__ __forceinline__ float ftanh(float x) {
    float e = __expf(-2.f * fabsf(x));
    float r = __fdividef(1.f - e, 1.f + e);
    return copysignf(r, x);
}

template<int N> __device__ __forceinline__ void vmwait() {
    if constexpr (N == 0)       asm volatile("s_waitcnt vmcnt(0)" ::: "memory");
    else if constexpr (N == 2)  asm volatile("s_waitcnt vmcnt(2)" ::: "memory");
    else if constexpr (N == 4)  asm volatile("s_waitcnt vmcnt(4)" ::: "memory");
    else if constexpr (N == 8)  asm volatile("s_waitcnt vmcnt(8)" ::: "memory");
    else                        asm volatile("s_waitcnt vmcnt(16)" ::: "memory");
}

// fused epilogue, shared by all GEMM kernels
template<int EPI>
__device__ __forceinline__ void epilogue_one(
    float val, int r, int c,
    float* __restrict__ outf, u16* __restrict__ outb,
    u16* __restrict__ zrb, const u16* __restrict__ auxb, int outRow0)
{
    if (EPI == 1) {
        float v = ftanh(val);
        size_t o = (size_t)(outRow0 + r) * H + c;
        outf[o] = v; outb[o] = f2b(v);
    } else if (EPI == 0) {
        if (c < H) {
            float z = sigm(val);
            zrb[(size_t)r * 1024 + c] = f2b(z);
            float hs = 0.f;
#pragma unroll
            for (int ch = 0; ch < 4; ++ch)
                hs += b2f(auxb[(size_t)(4 * r + ch) * H + c]);
            zrb[(size_t)r * 1024 + H + c] = f2b(hs);
        } else {
            float rr = sigm(val);
            int cc = c - H;
#pragma unroll
            for (int ch = 0; ch < 4; ++ch)
                outb[(size_t)r * 2048 + ch * H + cc] =
                    f2b(rr * b2f(auxb[(size_t)(4 * r + ch) * H + cc]));
        }
    } else { // EPI == 2
        float hc = ftanh(val);
        float z  = b2f(zrb[(size_t)r * 1024 + c]);
        float hs = b2f(zrb[(size_t)r * 1024 + H + c]);
        float v  = hs * z + (1.f - z) * hc;
        size_t o = (size_t)(outRow0 + r) * H + c;
        outf[o] = v; outb[o] = f2b(v);
    }
}

// ---------------- fp32 -> bf16 conversion (vectorized) ----------------
__global__ void cvt_kernel(const float* __restrict__ src, u16* __restrict__ dst, int n4) {
    int i = blockIdx.x * blockDim.x + threadIdx.x;
    int st = gridDim.x * blockDim.x;
    for (; i < n4; i += st) {
        float4 v = ((const float4*)src)[i];
        ushort4 o;
        o.x = f2b(v.x); o.y = f2b(v.y); o.z = f2b(v.z); o.w = f2b(v.w);
        ((ushort4*)dst)[i] = o;
    }
}

// ============ 512-thread 256x256 kernel (largest levels): 8 waves, BK=32 =====
// Same AUDITED schedule as gemm512/gemm_bt: NBUF=4 ring, depth-2 prefetch,
// counted vmcnt (8/4/0 — L=4 loads/thread/stage), ONE barrier/iter.
// Geometry change only: each wave owns a 128x64 tile -> acc[8][4] (128 VGPR),
// 32 MFMA : 12 ds_read_b128 per iter (2.67 ratio vs gemm512's 1.33).
// 128 KB LDS -> 1 block/CU, 8 waves; __launch_bounds__(512,2) caps VGPR at 256.
// Swizzle identical to audited BK=32 path (zero bank conflicts measured).
template<int EPI>
__global__ __launch_bounds__(512, 2) void gemm256(
    const u16* __restrict__ A, int lda, int M, int K,
    const u16* __restrict__ Bm,
    const float* __restrict__ bias,
    float* __restrict__ outf,
    u16*  __restrict__ outb,
    u16*  __restrict__ zrb,
    const u16* __restrict__ auxb,
    int outRow0)
{
    __shared__ u16 As[4][256 * 32];
    __shared__ u16 Bs[4][256 * 32];

    const int tid  = threadIdx.x;
    const int lane = tid & 63;
    const int wave = tid >> 6;        // 0..7
    const int wm = wave >> 2;         // 0..1 -> 128-row half
    const int wn = wave & 3;          // 0..3 -> 64-col quarter

    int bx, by;
    {
        const int gx = gridDim.x, gy = gridDim.y;
        int p = blockIdx.y * gx + blockIdx.x;
        if ((gy & 7) == 0) {
            int xcd = p & 7, slot = p >> 3;
            bx = slot % gx;
            by = (slot / gx) * 8 + xcd;
        } else { bx = blockIdx.x; by = blockIdx.y; }
    }
    const int row0 = by * 256;
    const int col0 = bx * 256;

    auto stage = [&](int b, int kt) {
#pragma unroll
        for (int j = 0; j < 2; ++j) {
            int e8  = j * 512 + tid;        // 1024 16B-units per tile
            int row = e8 >> 2;              // 0..255
            int jc  = e8 & 3;
            int js  = jc ^ ((row >> 1) & 3);
            int ar = row0 + row; if (ar >= M) ar = M - 1;
            const u16* ga = A + (size_t)ar * lda + kt + js * 8;
            __builtin_amdgcn_global_load_lds(
                (const __attribute__((address_space(1))) void*)ga,
                (__attribute__((address_space(3))) void*)(&As[b][e8 * 8]), 16, 0, 0);
            int br = col0 + row;
            const u16* gb = Bm + (size_t)br * K + kt + js * 8;
            __builtin_amdgcn_global_load_lds(
                (const __attribute__((address_space(1))) void*)gb,
                (__attribute__((address_space(3))) void*)(&Bs[b][e8 * 8]), 16, 0, 0);
        }
    };

    f32x4 acc[8][4] = {};

    const int nt = K / 32;
    stage(0, 0);
    if (nt > 1) stage(1, 32);

    const int rl = lane & 15;
    const int qq = lane >> 4;
    for (int t = 0; t < nt; ++t) {
        if (t + 2 < nt) {
            stage((t + 2) & 3, (t + 2) * 32);
            vmwait<8>();
        } else if (t + 2 == nt) {
            vmwait<4>();
        } else {
            vmwait<0>();
        }
        __builtin_amdgcn_s_barrier();
        asm volatile("" ::: "memory");

        const u16* as = As[t & 3];
        const u16* bs = Bs[t & 3];
        bf16x8 bfr[4];
#pragma unroll
        for (int ni = 0; ni < 4; ++ni) {
            int brow = wn * 64 + ni * 16 + rl;
            int u = qq ^ ((brow >> 1) & 3);
            bfr[ni] = *(const bf16x8*)&bs[brow * 32 + u * 8];
        }
#pragma unroll
        for (int mi = 0; mi < 8; ++mi) {
            int arow = wm * 128 + mi * 16 + rl;
            int u = qq ^ ((arow >> 1) & 3);
            bf16x8 af = *(const bf16x8*)&as[arow * 32 + u * 8];
#pragma unroll
            for (int ni = 0; ni < 4; ++ni)
                acc[mi][ni] = __builtin_amdgcn_mfma_f32_16x16x32_bf16(
                    af, bfr[ni], acc[mi][ni], 0, 0, 0);
        }
    }

    const int rq = lane >> 4;
    float bcol[4];
#pragma unroll
    for (int ni = 0; ni < 4; ++ni)
        bcol[ni] = bias[col0 + wn * 64 + ni * 16 + rl];

#pragma unroll
    for (int mi = 0; mi < 8; ++mi) {
#pragma unroll
        for (int ni = 0; ni < 4; ++ni) {
            const int c = col0 + wn * 64 + ni * 16 + rl;
#pragma unroll
            for (int q = 0; q < 4; ++q) {
                int r = row0 + wm * 128 + mi * 16 + rq * 4 + q;
                if (r >= M) continue;
                epilogue_one<EPI>(acc[mi][ni][q] + bcol[ni], r, c,
                                  outf, outb, zrb, auxb, outRow0);
            }
        }
    }
}

// ============ 512-thread 128x128 kernel (mid levels): 8 waves, BK=32 =========
template<int EPI>
__global__ __launch_bounds__(512) void gemm512(
    const u16* __restrict__ A, int lda, int M, int K,
    const u16* __restrict__ Bm,
    const float* __restrict__ bias,
    float* __restrict__ outf,
    u16*  __restrict__ outb,
    u16*  __restrict__ zrb,
    const u16* __restrict__ auxb,
    int outRow0)
{
    __shared__ u16 As[4][128 * 32];
    __shared__ u16 Bs[4][128 * 32];

    const int tid  = threadIdx.x;
    const int lane = tid & 63;
    const int wave = tid >> 6;        // 0..7
    const int wm = wave >> 2;         // 0..1 -> 64-row half
    const int wn = wave & 3;          // 0..3 -> 32-col quarter

    int bx, by;
    {
        const int gx = gridDim.x, gy = gridDim.y;
        int p = blockIdx.y * gx + blockIdx.x;
        if ((gy & 7) == 0) {
            int xcd = p & 7, slot = p >> 3;
            bx = slot % gx;
            by = (slot / gx) * 8 + xcd;
        } else { bx = blockIdx.x; by = blockIdx.y; }
    }
    const int row0 = by * 128;
    const int col0 = bx * 128;

    auto stage = [&](int b, int kt) {
        int e8  = tid;                  // 512 units, 1/thread
        int row = e8 >> 2;              // 0..127
        int jc  = e8 & 3;
        int js  = jc ^ ((row >> 1) & 3);
        int ar = row0 + row; if (ar >= M) ar = M - 1;
        const u16* ga = A + (size_t)ar * lda + kt + js * 8;
        __builtin_amdgcn_global_load_lds(
            (const __attribute__((address_space(1))) void*)ga,
            (__attribute__((address_space(3))) void*)(&As[b][e8 * 8]), 16, 0, 0);
        int br = col0 + row;
        const u16* gb = Bm + (size_t)br * K + kt + js * 8;
        __builtin_amdgcn_global_load_lds(
            (const __attribute__((address_space(1))) void*)gb,
            (__attribute__((address_space(3))) void*)(&Bs[b][e8 * 8]), 16, 0, 0);
    };

    f32x4 acc[4][2] = {};

    const int nt = K / 32;
    stage(0, 0);
    stage(1, 32);

    const int rl = lane & 15;
    const int qq = lane >> 4;
    for (int t = 0; t < nt; ++t) {
        if (t + 2 < nt) {
            stage((t + 2) & 3, (t + 2) * 32);
            vmwait<4>();
        } else if (t + 2 == nt) {
            vmwait<2>();
        } else {
            vmwait<0>();
        }
        __builtin_amdgcn_s_barrier();
        asm volatile("" ::: "memory");

        const u16* as = As[t & 3];
        const u16* bs = Bs[t & 3];
        bf16x8 af[4], bfr[2];
#pragma unroll
        for (int mi = 0; mi < 4; ++mi) {
            int arow = wm * 64 + mi * 16 + rl;
            int u = qq ^ ((arow >> 1) & 3);
            af[mi] = *(const bf16x8*)&as[arow * 32 + u * 8];
        }
#pragma unroll
        for (int ni = 0; ni < 2; ++ni) {
            int brow = wn * 32 + ni * 16 + rl;
            int u = qq ^ ((brow >> 1) & 3);
            bfr[ni] = *(const bf16x8*)&bs[brow * 32 + u * 8];
        }
#pragma unroll
        for (int mi = 0; mi < 4; ++mi)
#pragma unroll
            for (int ni = 0; ni < 2; ++ni)
                acc[mi][ni] = __builtin_amdgcn_mfma_f32_16x16x32_bf16(
                    af[mi], bfr[ni], acc[mi][ni], 0, 0, 0);
    }

    const int rq = lane >> 4;
    float bcol[2];
#pragma unroll
    for (int ni = 0; ni < 2; ++ni)
        bcol[ni] = bias[col0 + wn * 32 + ni * 16 + rl];

#pragma unroll
    for (int mi = 0; mi < 4; ++mi) {
#pragma unroll
        for (int ni = 0; ni < 2; ++ni) {
            const int c = col0 + wn * 32 + ni * 16 + rl;
#pragma unroll
            for (int q = 0; q < 4; ++q) {
                int r = row0 + wm * 64 + mi * 16 + rq * 4 + q;
                if (r >= M) continue;
                epilogue_one<EPI>(acc[mi][ni][q] + bcol[ni], r, c,
                                  outf, outb, zrb, auxb, outRow0);
            }
        }
    }
}

// ============ 256-thread 128x128 kernel (small levels) — verified R7 ========
template<int EPI, int BK>
__global__ __launch_bounds__(256) void gemm_bt(
    const u16* __restrict__ A, int lda, int M, int K,
    const u16* __restrict__ Bm,
    const float* __restrict__ bias,
    float* __restrict__ outf,
    u16*  __restrict__ outb,
    u16*  __restrict__ zrb,
    const u16* __restrict__ auxb,
    int outRow0)
{
    constexpr int UPR = BK / 8;
    constexpr int L   = 2 * (128 * UPR) / 256;

    __shared__ u16 As[4][128 * BK];
    __shared__ u16 Bs[4][128 * BK];

    const int tid  = threadIdx.x;
    const int lane = tid & 63;
    const int wave = tid >> 6;
    const int wm = wave >> 1, wn = wave & 1;

    int bx, by;
    {
        const int gx = gridDim.x, gy = gridDim.y;
        int p = blockIdx.y * gx + blockIdx.x;
        if ((gy & 7) == 0) {
            int xcd = p & 7, slot = p >> 3;
            bx = slot % gx;
            by = (slot / gx) * 8 + xcd;
        } else { bx = blockIdx.x; by = blockIdx.y; }
    }
    const int row0 = by * 128;
    const int col0 = bx * 128;

    auto stage = [&](int b, int kt) {
#pragma unroll
        for (int j = 0; j < (128 * UPR) / 256; ++j) {
            int e8  = j * 256 + tid;
            int row = e8 / UPR;
            int jc  = e8 % UPR;
            int js  = (BK == 32) ? (jc ^ ((row >> 1) & 3)) : (jc ^ (row & 7));
            int ar = row0 + row; if (ar >= M) ar = M - 1;
            const u16* ga = A + (size_t)ar * lda + kt + js * 8;
            __builtin_amdgcn_global_load_lds(
                (const __attribute__((address_space(1))) void*)ga,
                (__attribute__((address_space(3))) void*)(&As[b][e8 * 8]), 16, 0, 0);
            int br = col0 + row;
            const u16* gb = Bm + (size_t)br * K + kt + js * 8;
            __builtin_amdgcn_global_load_lds(
                (const __attribute__((address_space(1))) void*)gb,
                (__attribute__((address_space(3))) void*)(&Bs[b][e8 * 8]), 16, 0, 0);
        }
    };

    f32x4 acc[4][4] = {};

    const int nt = K / BK;
    stage(0, 0);
    if (nt > 1) stage(1, BK);

    const int rl = lane & 15;
    const int qq = lane >> 4;
    for (int t = 0; t < nt; ++t) {
        if (t + 2 < nt) {
            stage((t + 2) & 3, (t + 2) * BK);
            vmwait<2 * L>();
        } else if (t + 2 == nt) {
            vmwait<L>();
        } else {
            vmwait<0>();
        }
        __builtin_amdgcn_s_barrier();
        asm volatile("" ::: "memory");

        const u16* as = As[t & 3];
        const u16* bs = Bs[t & 3];
#pragma unroll
        for (int ks = 0; ks < BK / 32; ++ks) {
            bf16x8 af[4], bfr[4];
#pragma unroll
            for (int mi = 0; mi < 4; ++mi) {
                int arow = wm * 64 + mi * 16 + rl;
                int u = (BK == 32) ? (qq ^ ((arow >> 1) & 3))
                                   : ((ks * 4 + qq) ^ (arow & 7));
                af[mi] = *(const bf16x8*)&as[arow * BK + u * 8];
            }
#pragma unroll
            for (int ni = 0; ni < 4; ++ni) {
                int brow = wn * 64 + ni * 16 + rl;
                int u = (BK == 32) ? (qq ^ ((brow >> 1) & 3))
                                   : ((ks * 4 + qq) ^ (brow & 7));
                bfr[ni] = *(const bf16x8*)&bs[brow * BK + u * 8];
            }
#pragma unroll
            for (int mi = 0; mi < 4; ++mi)
#pragma unroll
                for (int ni = 0; ni < 4; ++ni)
                    acc[mi][ni] = __builtin_amdgcn_mfma_f32_16x16x32_bf16(
                        af[mi], bfr[ni], acc[mi][ni], 0, 0, 0);
        }
    }

    const int rq = lane >> 4;
    float bcol[4];
#pragma unroll
    for (int ni = 0; ni < 4; ++ni)
        bcol[ni] = bias[col0 + wn * 64 + ni * 16 + rl];

#pragma unroll
    for (int mi = 0; mi < 4; ++mi) {
#pragma unroll
        for (int ni = 0; ni < 4; ++ni) {
            const int c = col0 + wn * 64 + ni * 16 + rl;
#pragma unroll
            for (int q = 0; q < 4; ++q) {
                int r = row0 + wm * 64 + mi * 16 + rq * 4 + q;
                if (r >= M) continue;
                epilogue_one<EPI>(acc[mi][ni][q] + bcol[ni], r, c,
                                  outf, outb, zrb, auxb, outRow0);
            }
        }
    }
}

extern "C" void kernel_launch(void* const* d_in, const int* in_sizes, int n_in,
                              void* d_out, int out_size, void* d_ws, size_t ws_size,
                              hipStream_t stream) {
    const float* x     = (const float*)d_in[0];
    const float* Ww    = (const float*)d_in[1];
    const float* Wb    = (const float*)d_in[2];
    const float* Uzr_w = (const float*)d_in[3];
    const float* Uzr_b = (const float*)d_in[4];
    const float* Uh_w  = (const float*)d_in[5];
    const float* Uh_b  = (const float*)d_in[6];
    float* out = (float*)d_out;

    char* ws = (char*)d_ws;
    size_t off = 0;
    u16* hb   = (u16*)(ws + off); off += (size_t)NNODES * H * 2;       // 89.5 MB
    u16* zr   = (u16*)(ws + off); off += (size_t)16384 * 1024 * 2;     // 32 MB (bf16 z+hsum)
    u16* rhxb = (u16*)(ws + off); off += (size_t)16384 * 2048 * 2;     // 64 MB (rh / xb union)
    u16* Wwb  = (u16*)(ws + off); off += (size_t)512 * 512 * 2;
    u16* Uzrb = (u16*)(ws + off); off += (size_t)1024 * 2048 * 2;
    u16* Uhb  = (u16*)(ws + off); off += (size_t)512 * 2048 * 2;

    // 1) convert weights + leaf x to bf16
    cvt_kernel<<<dim3(256), 256, 0, stream>>>(Ww, Wwb, 512 * 512 / 4);
    cvt_kernel<<<dim3(2048), 256, 0, stream>>>(Uzr_w, Uzrb, 1024 * 2048 / 4);
    cvt_kernel<<<dim3(1024), 256, 0, stream>>>(Uh_w, Uhb, 512 * 2048 / 4);
    cvt_kernel<<<dim3(8192), 256, 0, stream>>>(x + (size_t)LEAF0 * H, rhxb,
                                               NLEAF * H / 4);

    // 2) leaf GEMM: h = tanh(x @ Ww^T + Wb) for leaves only — 256x256 tiles
    gemm256<1><<<dim3(H / 256, NLEAF / 256), 512, 0, stream>>>(
        rhxb, H, NLEAF, H, Wwb, Wb, out, hb, nullptr, nullptr, LEAF0);

    // 3) levels 7..0
    static const int pow4[9] = {1, 4, 16, 64, 256, 1024, 4096, 16384, 65536};
    int starts[10]; starts[0] = 0;
    for (int l = 0; l < 9; ++l) starts[l + 1] = starts[l] + pow4[l];

    for (int l = 7; l >= 0; --l) {
        int s = starts[l], m = pow4[l];
        int cs = 4 * s + 1;  // children rows are contiguous: [cs, cs+4m)
        if (m >= 16384) {
            // largest level: 256x256 tiles, full grid (G1: 4x64=256 blocks)
            gemm256<0><<<dim3(1024 / 256, m / 256), 512, 0, stream>>>(
                hb + (size_t)cs * H, 2048, m, 2048, Uzrb, Uzr_b,
                nullptr, rhxb, zr, hb + (size_t)cs * H, 0);
            gemm256<2><<<dim3(H / 256, m / 256), 512, 0, stream>>>(
                rhxb, 2048, m, 2048, Uhb, Uh_b,
                out, hb, zr, nullptr, s);
        } else if (m >= 4096) {
            int gm = (m + 127) / 128;
            // mid levels: 512-thr 128x128 kernel, 16 waves/CU
            gemm512<0><<<dim3(1024 / 128, gm), 512, 0, stream>>>(
                hb + (size_t)cs * H, 2048, m, 2048, Uzrb, Uzr_b,
                nullptr, rhxb, zr, hb + (size_t)cs * H, 0);
            gemm512<2><<<dim3(H / 128, gm), 512, 0, stream>>>(
                rhxb, 2048, m, 2048, Uhb, Uh_b,
                out, hb, zr, nullptr, s);
        } else {
            int gm = (m + 127) / 128;
            // small/mid levels: few blocks -> 256-thr BK64 (verified R7 path)
            gemm_bt<0, 64><<<dim3(1024 / 128, gm), 256, 0, stream>>>(
                hb + (size_t)cs * H, 2048, m, 2048, Uzrb, Uzr_b,
                nullptr, rhxb, zr, hb + (size_t)cs * H, 0);
            gemm_bt<2, 64><<<dim3(H / 128, gm), 256, 0, stream>>>(
                rhxb, 2048, m, 2048, Uhb, Uh_b,
                out, hb, zr, nullptr, s);
        }
    }
}

// Round 2
// 940.185 us; speedup vs baseline: 1.1028x; 1.1028x over previous
//
#include <hip/hip_runtime.h>
#include <math.h>

#define H 512
typedef unsigned short u16;
typedef __attribute__((ext_vector_type(8))) short bf16x8;
typedef __attribute__((ext_vector_type(4))) float f32x4;

constexpr int LEAF0  = 21845;   // starts[8]
constexpr int NLEAF  = 65536;
constexpr int NNODES = 87381;

__device__ __forceinline__ u16 f2b(float f) {
    union { float f; unsigned u; } v; v.f = f;
    unsigned r = v.u + 0x7fffu + ((v.u >> 16) & 1u);  // RNE
    return (u16)(r >> 16);
}
__device__ __forceinline__ float b2f(u16 b) {
    union { unsigned u; float f; } v; v.u = ((unsigned)b) << 16; return v.f;
}
__device__ __forceinline__ float sigm(float x) {
    return __fdividef(1.f, 1.f + __expf(-x));
}
__device__ __forceinline__ float ftanh(float x) {
    float e = __expf(-2.f * fabsf(x));
    float r = __fdividef(1.f - e, 1.f + e);
    return copysignf(r, x);
}

template<int N> __device__ __forceinline__ void vmwait() {
    if constexpr (N == 0)       asm volatile("s_waitcnt vmcnt(0)" ::: "memory");
    else if constexpr (N == 2)  asm volatile("s_waitcnt vmcnt(2)" ::: "memory");
    else if constexpr (N == 3)  asm volatile("s_waitcnt vmcnt(3)" ::: "memory");
    else if constexpr (N == 4)  asm volatile("s_waitcnt vmcnt(4)" ::: "memory");
    else if constexpr (N == 6)  asm volatile("s_waitcnt vmcnt(6)" ::: "memory");
    else if constexpr (N == 8)  asm volatile("s_waitcnt vmcnt(8)" ::: "memory");
    else                        asm volatile("s_waitcnt vmcnt(16)" ::: "memory");
}

// fused epilogue, shared by all GEMM kernels
template<int EPI>
__device__ __forceinline__ void epilogue_one(
    float val, int r, int c,
    float* __restrict__ outf, u16* __restrict__ outb,
    u16* __restrict__ zrb, const u16* __restrict__ auxb, int outRow0)
{
    if (EPI == 1) {
        float v = ftanh(val);
        size_t o = (size_t)(outRow0 + r) * H + c;
        outf[o] = v; outb[o] = f2b(v);
    } else if (EPI == 0) {
        if (c < H) {
            float z = sigm(val);
            zrb[(size_t)r * 1024 + c] = f2b(z);
            float hs = 0.f;
#pragma unroll
            for (int ch = 0; ch < 4; ++ch)
                hs += b2f(auxb[(size_t)(4 * r + ch) * H + c]);
            zrb[(size_t)r * 1024 + H + c] = f2b(hs);
        } else {
            float rr = sigm(val);
            int cc = c - H;
#pragma unroll
            for (int ch = 0; ch < 4; ++ch)
                outb[(size_t)r * 2048 + ch * H + cc] =
                    f2b(rr * b2f(auxb[(size_t)(4 * r + ch) * H + cc]));
        }
    } else { // EPI == 2
        float hc = ftanh(val);
        float z  = b2f(zrb[(size_t)r * 1024 + c]);
        float hs = b2f(zrb[(size_t)r * 1024 + H + c]);
        float v  = hs * z + (1.f - z) * hc;
        size_t o = (size_t)(outRow0 + r) * H + c;
        outf[o] = v; outb[o] = f2b(v);
    }
}

// ---------------- fp32 -> bf16 conversion (vectorized) ----------------
__global__ void cvt_kernel(const float* __restrict__ src, u16* __restrict__ dst, int n4) {
    int i = blockIdx.x * blockDim.x + threadIdx.x;
    int st = gridDim.x * blockDim.x;
    for (; i < n4; i += st) {
        float4 v = ((const float4*)src)[i];
        ushort4 o;
        o.x = f2b(v.x); o.y = f2b(v.y); o.z = f2b(v.z); o.w = f2b(v.w);
        ((ushort4*)dst)[i] = o;
    }
}

// ============ 512-thread 256x128 kernel (big levels): 16 waves/CU ===========
// Wave tile 64x64 (acc[4][4] = 64 AGPR; total regs ~120 <= 128 -> 4 waves/SIMD).
// NBUF=3 ring (72 KB LDS -> 2 blocks/CU), depth-2 prefetch, counted vmcnt
// (3/0), ONE barrier/iter. NBUF=3 requires stage(t+2) AFTER the barrier:
// the iter-t barrier proves all waves finished reading tile t-1 (its buffer
// is what t+2 overwrites); tile-t visibility holds because every wave does
// vmwait<3> (draining its own tile-t loads) BEFORE that same barrier.
// Swizzle identical to the audited BK=32 path (zero bank conflicts measured).
template<int EPI>
__global__ __launch_bounds__(512, 4) void gemmw(
    const u16* __restrict__ A, int lda, int M, int K,
    const u16* __restrict__ Bm,
    const float* __restrict__ bias,
    float* __restrict__ outf,
    u16*  __restrict__ outb,
    u16*  __restrict__ zrb,
    const u16* __restrict__ auxb,
    int outRow0)
{
    __shared__ u16 As[3][256 * 32];   // 48 KB
    __shared__ u16 Bs[3][128 * 32];   // 24 KB

    const int tid  = threadIdx.x;
    const int lane = tid & 63;
    const int wave = tid >> 6;        // 0..7
    const int wm = wave >> 1;         // 0..3 -> 64-row band of 256
    const int wn = wave & 1;          // 0..1 -> 64-col half of 128

    int bx, by;
    {
        const int gx = gridDim.x, gy = gridDim.y;
        int p = blockIdx.y * gx + blockIdx.x;
        if ((gy & 7) == 0) {
            int xcd = p & 7, slot = p >> 3;
            bx = slot % gx;
            by = (slot / gx) * 8 + xcd;
        } else { bx = blockIdx.x; by = blockIdx.y; }
    }
    const int row0 = by * 256;
    const int col0 = bx * 128;

    auto stage = [&](int b, int kt) {
        // A tile: 256 rows x 32 -> 1024 16B-units (2/thread)
#pragma unroll
        for (int j = 0; j < 2; ++j) {
            int e8  = j * 512 + tid;
            int row = e8 >> 2;              // 0..255
            int jc  = e8 & 3;
            int js  = jc ^ ((row >> 1) & 3);
            int ar = row0 + row; if (ar >= M) ar = M - 1;
            const u16* ga = A + (size_t)ar * lda + kt + js * 8;
            __builtin_amdgcn_global_load_lds(
                (const __attribute__((address_space(1))) void*)ga,
                (__attribute__((address_space(3))) void*)(&As[b][e8 * 8]), 16, 0, 0);
        }
        // B tile: 128 rows x 32 -> 512 16B-units (1/thread)
        {
            int e8  = tid;
            int row = e8 >> 2;              // 0..127
            int jc  = e8 & 3;
            int js  = jc ^ ((row >> 1) & 3);
            int br = col0 + row;
            const u16* gb = Bm + (size_t)br * K + kt + js * 8;
            __builtin_amdgcn_global_load_lds(
                (const __attribute__((address_space(1))) void*)gb,
                (__attribute__((address_space(3))) void*)(&Bs[b][e8 * 8]), 16, 0, 0);
        }
    };

    f32x4 acc[4][4] = {};

    const int nt = K / 32;
    stage(0, 0);
    if (nt > 1) stage(1, 32);

    const int rl = lane & 15;
    const int qq = lane >> 4;
    for (int t = 0; t < nt; ++t) {
        if (t + 1 < nt) vmwait<3>();   // drain tile t's 3 loads; t+1's stay in flight
        else            vmwait<0>();
        __builtin_amdgcn_s_barrier();
        asm volatile("" ::: "memory");
        if (t + 2 < nt) stage((t + 2) % 3, (t + 2) * 32);

        const u16* as = As[t % 3];
        const u16* bs = Bs[t % 3];
        bf16x8 af[4], bfr[4];
#pragma unroll
        for (int mi = 0; mi < 4; ++mi) {
            int arow = wm * 64 + mi * 16 + rl;
            int u = qq ^ ((arow >> 1) & 3);
            af[mi] = *(const bf16x8*)&as[arow * 32 + u * 8];
        }
#pragma unroll
        for (int ni = 0; ni < 4; ++ni) {
            int brow = wn * 64 + ni * 16 + rl;
            int u = qq ^ ((brow >> 1) & 3);
            bfr[ni] = *(const bf16x8*)&bs[brow * 32 + u * 8];
        }
#pragma unroll
        for (int mi = 0; mi < 4; ++mi)
#pragma unroll
            for (int ni = 0; ni < 4; ++ni)
                acc[mi][ni] = __builtin_amdgcn_mfma_f32_16x16x32_bf16(
                    af[mi], bfr[ni], acc[mi][ni], 0, 0, 0);
    }

    const int rq = lane >> 4;
    float bcol[4];
#pragma unroll
    for (int ni = 0; ni < 4; ++ni)
        bcol[ni] = bias[col0 + wn * 64 + ni * 16 + rl];

#pragma unroll
    for (int mi = 0; mi < 4; ++mi) {
#pragma unroll
        for (int ni = 0; ni < 4; ++ni) {
            const int c = col0 + wn * 64 + ni * 16 + rl;
#pragma unroll
            for (int q = 0; q < 4; ++q) {
                int r = row0 + wm * 64 + mi * 16 + rq * 4 + q;
                if (r >= M) continue;
                epilogue_one<EPI>(acc[mi][ni][q] + bcol[ni], r, c,
                                  outf, outb, zrb, auxb, outRow0);
            }
        }
    }
}

// ============ 512-thread 128x128 kernel (mid levels): 8 waves, BK=32 =========
template<int EPI>
__global__ __launch_bounds__(512) void gemm512(
    const u16* __restrict__ A, int lda, int M, int K,
    const u16* __restrict__ Bm,
    const float* __restrict__ bias,
    float* __restrict__ outf,
    u16*  __restrict__ outb,
    u16*  __restrict__ zrb,
    const u16* __restrict__ auxb,
    int outRow0)
{
    __shared__ u16 As[4][128 * 32];
    __shared__ u16 Bs[4][128 * 32];

    const int tid  = threadIdx.x;
    const int lane = tid & 63;
    const int wave = tid >> 6;        // 0..7
    const int wm = wave >> 2;         // 0..1 -> 64-row half
    const int wn = wave & 3;          // 0..3 -> 32-col quarter

    int bx, by;
    {
        const int gx = gridDim.x, gy = gridDim.y;
        int p = blockIdx.y * gx + blockIdx.x;
        if ((gy & 7) == 0) {
            int xcd = p & 7, slot = p >> 3;
            bx = slot % gx;
            by = (slot / gx) * 8 + xcd;
        } else { bx = blockIdx.x; by = blockIdx.y; }
    }
    const int row0 = by * 128;
    const int col0 = bx * 128;

    auto stage = [&](int b, int kt) {
        int e8  = tid;                  // 512 units, 1/thread
        int row = e8 >> 2;              // 0..127
        int jc  = e8 & 3;
        int js  = jc ^ ((row >> 1) & 3);
        int ar = row0 + row; if (ar >= M) ar = M - 1;
        const u16* ga = A + (size_t)ar * lda + kt + js * 8;
        __builtin_amdgcn_global_load_lds(
            (const __attribute__((address_space(1))) void*)ga,
            (__attribute__((address_space(3))) void*)(&As[b][e8 * 8]), 16, 0, 0);
        int br = col0 + row;
        const u16* gb = Bm + (size_t)br * K + kt + js * 8;
        __builtin_amdgcn_global_load_lds(
            (const __attribute__((address_space(1))) void*)gb,
            (__attribute__((address_space(3))) void*)(&Bs[b][e8 * 8]), 16, 0, 0);
    };

    f32x4 acc[4][2] = {};

    const int nt = K / 32;
    stage(0, 0);
    stage(1, 32);

    const int rl = lane & 15;
    const int qq = lane >> 4;
    for (int t = 0; t < nt; ++t) {
        if (t + 2 < nt) {
            stage((t + 2) & 3, (t + 2) * 32);
            vmwait<4>();
        } else if (t + 2 == nt) {
            vmwait<2>();
        } else {
            vmwait<0>();
        }
        __builtin_amdgcn_s_barrier();
        asm volatile("" ::: "memory");

        const u16* as = As[t & 3];
        const u16* bs = Bs[t & 3];
        bf16x8 af[4], bfr[2];
#pragma unroll
        for (int mi = 0; mi < 4; ++mi) {
            int arow = wm * 64 + mi * 16 + rl;
            int u = qq ^ ((arow >> 1) & 3);
            af[mi] = *(const bf16x8*)&as[arow * 32 + u * 8];
        }
#pragma unroll
        for (int ni = 0; ni < 2; ++ni) {
            int brow = wn * 32 + ni * 16 + rl;
            int u = qq ^ ((brow >> 1) & 3);
            bfr[ni] = *(const bf16x8*)&bs[brow * 32 + u * 8];
        }
#pragma unroll
        for (int mi = 0; mi < 4; ++mi)
#pragma unroll
            for (int ni = 0; ni < 2; ++ni)
                acc[mi][ni] = __builtin_amdgcn_mfma_f32_16x16x32_bf16(
                    af[mi], bfr[ni], acc[mi][ni], 0, 0, 0);
    }

    const int rq = lane >> 4;
    float bcol[2];
#pragma unroll
    for (int ni = 0; ni < 2; ++ni)
        bcol[ni] = bias[col0 + wn * 32 + ni * 16 + rl];

#pragma unroll
    for (int mi = 0; mi < 4; ++mi) {
#pragma unroll
        for (int ni = 0; ni < 2; ++ni) {
            const int c = col0 + wn * 32 + ni * 16 + rl;
#pragma unroll
            for (int q = 0; q < 4; ++q) {
                int r = row0 + wm * 64 + mi * 16 + rq * 4 + q;
                if (r >= M) continue;
                epilogue_one<EPI>(acc[mi][ni][q] + bcol[ni], r, c,
                                  outf, outb, zrb, auxb, outRow0);
            }
        }
    }
}

// ============ 256-thread 128x128 kernel (small levels) — verified R7 ========
template<int EPI, int BK>
__global__ __launch_bounds__(256) void gemm_bt(
    const u16* __restrict__ A, int lda, int M, int K,
    const u16* __restrict__ Bm,
    const float* __restrict__ bias,
    float* __restrict__ outf,
    u16*  __restrict__ outb,
    u16*  __restrict__ zrb,
    const u16* __restrict__ auxb,
    int outRow0)
{
    constexpr int UPR = BK / 8;
    constexpr int L   = 2 * (128 * UPR) / 256;

    __shared__ u16 As[4][128 * BK];
    __shared__ u16 Bs[4][128 * BK];

    const int tid  = threadIdx.x;
    const int lane = tid & 63;
    const int wave = tid >> 6;
    const int wm = wave >> 1, wn = wave & 1;

    int bx, by;
    {
        const int gx = gridDim.x, gy = gridDim.y;
        int p = blockIdx.y * gx + blockIdx.x;
        if ((gy & 7) == 0) {
            int xcd = p & 7, slot = p >> 3;
            bx = slot % gx;
            by = (slot / gx) * 8 + xcd;
        } else { bx = blockIdx.x; by = blockIdx.y; }
    }
    const int row0 = by * 128;
    const int col0 = bx * 128;

    auto stage = [&](int b, int kt) {
#pragma unroll
        for (int j = 0; j < (128 * UPR) / 256; ++j) {
            int e8  = j * 256 + tid;
            int row = e8 / UPR;
            int jc  = e8 % UPR;
            int js  = (BK == 32) ? (jc ^ ((row >> 1) & 3)) : (jc ^ (row & 7));
            int ar = row0 + row; if (ar >= M) ar = M - 1;
            const u16* ga = A + (size_t)ar * lda + kt + js * 8;
            __builtin_amdgcn_global_load_lds(
                (const __attribute__((address_space(1))) void*)ga,
                (__attribute__((address_space(3))) void*)(&As[b][e8 * 8]), 16, 0, 0);
            int br = col0 + row;
            const u16* gb = Bm + (size_t)br * K + kt + js * 8;
            __builtin_amdgcn_global_load_lds(
                (const __attribute__((address_space(1))) void*)gb,
                (__attribute__((address_space(3))) void*)(&Bs[b][e8 * 8]), 16, 0, 0);
        }
    };

    f32x4 acc[4][4] = {};

    const int nt = K / BK;
    stage(0, 0);
    if (nt > 1) stage(1, BK);

    const int rl = lane & 15;
    const int qq = lane >> 4;
    for (int t = 0; t < nt; ++t) {
        if (t + 2 < nt) {
            stage((t + 2) & 3, (t + 2) * BK);
            vmwait<2 * L>();
        } else if (t + 2 == nt) {
            vmwait<L>();
        } else {
            vmwait<0>();
        }
        __builtin_amdgcn_s_barrier();
        asm volatile("" ::: "memory");

        const u16* as = As[t & 3];
        const u16* bs = Bs[t & 3];
#pragma unroll
        for (int ks = 0; ks < BK / 32; ++ks) {
            bf16x8 af[4], bfr[4];
#pragma unroll
            for (int mi = 0; mi < 4; ++mi) {
                int arow = wm * 64 + mi * 16 + rl;
                int u = (BK == 32) ? (qq ^ ((arow >> 1) & 3))
                                   : ((ks * 4 + qq) ^ (arow & 7));
                af[mi] = *(const bf16x8*)&as[arow * BK + u * 8];
            }
#pragma unroll
            for (int ni = 0; ni < 4; ++ni) {
                int brow = wn * 64 + ni * 16 + rl;
                int u = (BK == 32) ? (qq ^ ((brow >> 1) & 3))
                                   : ((ks * 4 + qq) ^ (brow & 7));
                bfr[ni] = *(const bf16x8*)&bs[brow * BK + u * 8];
            }
#pragma unroll
            for (int mi = 0; mi < 4; ++mi)
#pragma unroll
                for (int ni = 0; ni < 4; ++ni)
                    acc[mi][ni] = __builtin_amdgcn_mfma_f32_16x16x32_bf16(
                        af[mi], bfr[ni], acc[mi][ni], 0, 0, 0);
        }
    }

    const int rq = lane >> 4;
    float bcol[4];
#pragma unroll
    for (int ni = 0; ni < 4; ++ni)
        bcol[ni] = bias[col0 + wn * 64 + ni * 16 + rl];

#pragma unroll
    for (int mi = 0; mi < 4; ++mi) {
#pragma unroll
        for (int ni = 0; ni < 4; ++ni) {
            const int c = col0 + wn * 64 + ni * 16 + rl;
#pragma unroll
            for (int q = 0; q < 4; ++q) {
                int r = row0 + wm * 64 + mi * 16 + rq * 4 + q;
                if (r >= M) continue;
                epilogue_one<EPI>(acc[mi][ni][q] + bcol[ni], r, c,
                                  outf, outb, zrb, auxb, outRow0);
            }
        }
    }
}

extern "C" void kernel_launch(void* const* d_in, const int* in_sizes, int n_in,
                              void* d_out, int out_size, void* d_ws, size_t ws_size,
                              hipStream_t stream) {
    const float* x     = (const float*)d_in[0];
    const float* Ww    = (const float*)d_in[1];
    const float* Wb    = (const float*)d_in[2];
    const float* Uzr_w = (const float*)d_in[3];
    const float* Uzr_b = (const float*)d_in[4];
    const float* Uh_w  = (const float*)d_in[5];
    const float* Uh_b  = (const float*)d_in[6];
    float* out = (float*)d_out;

    char* ws = (char*)d_ws;
    size_t off = 0;
    u16* hb   = (u16*)(ws + off); off += (size_t)NNODES * H * 2;       // 89.5 MB
    u16* zr   = (u16*)(ws + off); off += (size_t)16384 * 1024 * 2;     // 32 MB (bf16 z+hsum)
    u16* rhxb = (u16*)(ws + off); off += (size_t)16384 * 2048 * 2;     // 64 MB (rh / xb union)
    u16* Wwb  = (u16*)(ws + off); off += (size_t)512 * 512 * 2;
    u16* Uzrb = (u16*)(ws + off); off += (size_t)1024 * 2048 * 2;
    u16* Uhb  = (u16*)(ws + off); off += (size_t)512 * 2048 * 2;

    // 1) convert weights + leaf x to bf16
    cvt_kernel<<<dim3(256), 256, 0, stream>>>(Ww, Wwb, 512 * 512 / 4);
    cvt_kernel<<<dim3(2048), 256, 0, stream>>>(Uzr_w, Uzrb, 1024 * 2048 / 4);
    cvt_kernel<<<dim3(1024), 256, 0, stream>>>(Uh_w, Uhb, 512 * 2048 / 4);
    cvt_kernel<<<dim3(8192), 256, 0, stream>>>(x + (size_t)LEAF0 * H, rhxb,
                                               NLEAF * H / 4);

    // 2) leaf GEMM: h = tanh(x @ Ww^T + Wb) — 256x128 tiles, 16 waves/CU
    gemmw<1><<<dim3(H / 128, NLEAF / 256), 512, 0, stream>>>(
        rhxb, H, NLEAF, H, Wwb, Wb, out, hb, nullptr, nullptr, LEAF0);

    // 3) levels 7..0
    static const int pow4[9] = {1, 4, 16, 64, 256, 1024, 4096, 16384, 65536};
    int starts[10]; starts[0] = 0;
    for (int l = 0; l < 9; ++l) starts[l + 1] = starts[l] + pow4[l];

    for (int l = 7; l >= 0; --l) {
        int s = starts[l], m = pow4[l];
        int cs = 4 * s + 1;  // children rows are contiguous: [cs, cs+4m)
        if (m >= 16384) {
            // largest level: 256x128 tiles (Uzr: 8x64=512 blocks -> 2/CU)
            gemmw<0><<<dim3(1024 / 128, m / 256), 512, 0, stream>>>(
                hb + (size_t)cs * H, 2048, m, 2048, Uzrb, Uzr_b,
                nullptr, rhxb, zr, hb + (size_t)cs * H, 0);
            gemmw<2><<<dim3(H / 128, m / 256), 512, 0, stream>>>(
                rhxb, 2048, m, 2048, Uhb, Uh_b,
                out, hb, zr, nullptr, s);
        } else if (m >= 4096) {
            int gm = (m + 127) / 128;
            // mid levels: 512-thr 128x128 kernel, 16 waves/CU
            gemm512<0><<<dim3(1024 / 128, gm), 512, 0, stream>>>(
                hb + (size_t)cs * H, 2048, m, 2048, Uzrb, Uzr_b,
                nullptr, rhxb, zr, hb + (size_t)cs * H, 0);
            gemm512<2><<<dim3(H / 128, gm), 512, 0, stream>>>(
                rhxb, 2048, m, 2048, Uhb, Uh_b,
                out, hb, zr, nullptr, s);
        } else {
            int gm = (m + 127) / 128;
            // small/mid levels: few blocks -> 256-thr BK64 (verified R7 path)
            gemm_bt<0, 64><<<dim3(1024 / 128, gm), 256, 0, stream>>>(
                hb + (size_t)cs * H, 2048, m, 2048, Uzrb, Uzr_b,
                nullptr, rhxb, zr, hb + (size_t)cs * H, 0);
            gemm_bt<2, 64><<<dim3(H / 128, gm), 256, 0, stream>>>(
                rhxb, 2048, m, 2048, Uhb, Uh_b,
                out, hb, zr, nullptr, s);
        }
    }
}

// Round 3
// 648.176 us; speedup vs baseline: 1.5997x; 1.4505x over previous
//
#include <hip/hip_runtime.h>
#include <math.h>

#define H 512
typedef unsigned short u16;
typedef __attribute__((ext_vector_type(8))) short bf16x8;
typedef __attribute__((ext_vector_type(4))) float f32x4;
typedef __attribute__((ext_vector_type(8))) unsigned short u16x8;

constexpr int LEAF0  = 21845;   // starts[8]
constexpr int NLEAF  = 65536;
constexpr int NNODES = 87381;

__device__ __forceinline__ u16 f2b(float f) {
    union { float f; unsigned u; } v; v.f = f;
    unsigned r = v.u + 0x7fffu + ((v.u >> 16) & 1u);  // RNE
    return (u16)(r >> 16);
}
__device__ __forceinline__ float b2f(u16 b) {
    union { unsigned u; float f; } v; v.u = ((unsigned)b) << 16; return v.f;
}
__device__ __forceinline__ float sigm(float x) {
    return __fdividef(1.f, 1.f + __expf(-x));
}
__device__ __forceinline__ float ftanh(float x) {
    float e = __expf(-2.f * fabsf(x));
    float r = __fdividef(1.f - e, 1.f + e);
    return copysignf(r, x);
}

template<int N> __device__ __forceinline__ void vmwait() {
    if constexpr (N == 0)       asm volatile("s_waitcnt vmcnt(0)" ::: "memory");
    else if constexpr (N == 2)  asm volatile("s_waitcnt vmcnt(2)" ::: "memory");
    else if constexpr (N == 3)  asm volatile("s_waitcnt vmcnt(3)" ::: "memory");
    else if constexpr (N == 4)  asm volatile("s_waitcnt vmcnt(4)" ::: "memory");
    else if constexpr (N == 6)  asm volatile("s_waitcnt vmcnt(6)" ::: "memory");
    else if constexpr (N == 8)  asm volatile("s_waitcnt vmcnt(8)" ::: "memory");
    else                        asm volatile("s_waitcnt vmcnt(16)" ::: "memory");
}

// ---------------- vectorized fused epilogue (per-lane, NC contiguous cols) --
// va: NC/4 f32x4 of pre-bias-added GEMM outputs for row gr, cols [gc0,gc0+NC)
// All global IO is 16-byte vector ops. Arithmetic order identical to the old
// scalar epilogue (ch 0..3 summation, same transcendentals) -> bit-identical.
template<int EPI, int NC>
__device__ __forceinline__ void epi_vec(
    const f32x4* va, int gr, int gc0,
    float* __restrict__ outf, u16* __restrict__ outb,
    u16* __restrict__ zrb, const u16* __restrict__ auxb, int outRow0)
{
    constexpr int NV = NC / 8;
    if constexpr (EPI == 1) {
        f32x4 ov[NC/4]; u16x8 hv[NV];
#pragma unroll
        for (int i = 0; i < NC; ++i) {
            float v = ftanh(va[i>>2][i&3]);
            ov[i>>2][i&3] = v; hv[i>>3][i&7] = f2b(v);
        }
        size_t o = (size_t)(outRow0 + gr) * H + gc0;
#pragma unroll
        for (int j = 0; j < NC/4; ++j) *(f32x4*)&outf[o + 4*j] = ov[j];
#pragma unroll
        for (int j = 0; j < NV; ++j) *(u16x8*)&outb[o + 8*j] = hv[j];
    } else if constexpr (EPI == 0) {
        if (gc0 < H) {
            u16x8 zv[NV]; f32x4 hs[NC/4];
#pragma unroll
            for (int i = 0; i < NC; ++i) {
                zv[i>>3][i&7] = f2b(sigm(va[i>>2][i&3]));
                hs[i>>2][i&3] = 0.f;
            }
#pragma unroll
            for (int ch = 0; ch < 4; ++ch) {
#pragma unroll
                for (int j = 0; j < NV; ++j) {
                    u16x8 cv = *(const u16x8*)&auxb[(size_t)(4*gr+ch)*H + gc0 + 8*j];
#pragma unroll
                    for (int k = 0; k < 8; ++k) {
                        int i = 8*j + k;
                        hs[i>>2][i&3] += b2f(cv[k]);
                    }
                }
            }
            u16x8 sv[NV];
#pragma unroll
            for (int i = 0; i < NC; ++i) sv[i>>3][i&7] = f2b(hs[i>>2][i&3]);
            size_t zo = (size_t)gr * 1024 + gc0;
#pragma unroll
            for (int j = 0; j < NV; ++j) *(u16x8*)&zrb[zo + 8*j] = zv[j];
#pragma unroll
            for (int j = 0; j < NV; ++j) *(u16x8*)&zrb[zo + H + 8*j] = sv[j];
        } else {
            f32x4 rr[NC/4];
#pragma unroll
            for (int i = 0; i < NC; ++i) rr[i>>2][i&3] = sigm(va[i>>2][i&3]);
            const int cc = gc0 - H;
#pragma unroll
            for (int ch = 0; ch < 4; ++ch) {
#pragma unroll
                for (int j = 0; j < NV; ++j) {
                    u16x8 cv = *(const u16x8*)&auxb[(size_t)(4*gr+ch)*H + cc + 8*j];
                    u16x8 ov;
#pragma unroll
                    for (int k = 0; k < 8; ++k) {
                        int i = 8*j + k;
                        ov[k] = f2b(rr[i>>2][i&3] * b2f(cv[k]));
                    }
                    *(u16x8*)&outb[(size_t)gr*2048 + ch*H + cc + 8*j] = ov;
                }
            }
        }
    } else { // EPI == 2
        size_t zo = (size_t)gr * 1024 + gc0;
        u16x8 zv[NV], sv[NV];
#pragma unroll
        for (int j = 0; j < NV; ++j) zv[j] = *(const u16x8*)&zrb[zo + 8*j];
#pragma unroll
        for (int j = 0; j < NV; ++j) sv[j] = *(const u16x8*)&zrb[zo + H + 8*j];
        f32x4 ov[NC/4]; u16x8 hv[NV];
#pragma unroll
        for (int i = 0; i < NC; ++i) {
            float hc = ftanh(va[i>>2][i&3]);
            float z  = b2f(zv[i>>3][i&7]);
            float v  = b2f(sv[i>>3][i&7]) * z + (1.f - z) * hc;
            ov[i>>2][i&3] = v; hv[i>>3][i&7] = f2b(v);
        }
        size_t o = (size_t)(outRow0 + gr) * H + gc0;
#pragma unroll
        for (int j = 0; j < NC/4; ++j) *(f32x4*)&outf[o + 4*j] = ov[j];
#pragma unroll
        for (int j = 0; j < NV; ++j) *(u16x8*)&outb[o + 8*j] = hv[j];
    }
}

// ---------------- fp32 -> bf16 conversion (vectorized) ----------------
__global__ void cvt_kernel(const float* __restrict__ src, u16* __restrict__ dst, int n4) {
    int i = blockIdx.x * blockDim.x + threadIdx.x;
    int st = gridDim.x * blockDim.x;
    for (; i < n4; i += st) {
        float4 v = ((const float4*)src)[i];
        ushort4 o;
        o.x = f2b(v.x); o.y = f2b(v.y); o.z = f2b(v.z); o.w = f2b(v.w);
        ((ushort4*)dst)[i] = o;
    }
}

// ============ 512-thread 256x128 kernel (big levels): 16 waves/CU ===========
// K-loop unchanged from R2 (audited): NBUF=3 ring, depth-2 prefetch, counted
// vmcnt (3/0), ONE barrier/iter, stage(t+2) after the barrier.
// NEW: per-wave LDS-transpose epilogue -> all global IO in 16B vector ops.
template<int EPI>
__global__ __launch_bounds__(512, 4) void gemmw(
    const u16* __restrict__ A, int lda, int M, int K,
    const u16* __restrict__ Bm,
    const float* __restrict__ bias,
    float* __restrict__ outf,
    u16*  __restrict__ outb,
    u16*  __restrict__ zrb,
    const u16* __restrict__ auxb,
    int outRow0)
{
    __shared__ __align__(16) char smem[3*256*32*2 + 3*128*32*2]; // 73728 B
    u16 (*As)[256*32] = reinterpret_cast<u16(*)[256*32]>(smem);
    u16 (*Bs)[128*32] = reinterpret_cast<u16(*)[128*32]>(smem + 3*256*32*2);

    const int tid  = threadIdx.x;
    const int lane = tid & 63;
    const int wave = tid >> 6;        // 0..7
    const int wm = wave >> 1;         // 0..3 -> 64-row band of 256
    const int wn = wave & 1;          // 0..1 -> 64-col half of 128

    int bx, by;
    {
        const int gx = gridDim.x, gy = gridDim.y;
        int p = blockIdx.y * gx + blockIdx.x;
        if ((gy & 7) == 0) {
            int xcd = p & 7, slot = p >> 3;
            bx = slot % gx;
            by = (slot / gx) * 8 + xcd;
        } else { bx = blockIdx.x; by = blockIdx.y; }
    }
    const int row0 = by * 256;
    const int col0 = bx * 128;

    auto stage = [&](int b, int kt) {
#pragma unroll
        for (int j = 0; j < 2; ++j) {
            int e8  = j * 512 + tid;
            int row = e8 >> 2;              // 0..255
            int jc  = e8 & 3;
            int js  = jc ^ ((row >> 1) & 3);
            int ar = row0 + row; if (ar >= M) ar = M - 1;
            const u16* ga = A + (size_t)ar * lda + kt + js * 8;
            __builtin_amdgcn_global_load_lds(
                (const __attribute__((address_space(1))) void*)ga,
                (__attribute__((address_space(3))) void*)(&As[b][e8 * 8]), 16, 0, 0);
        }
        {
            int e8  = tid;
            int row = e8 >> 2;              // 0..127
            int jc  = e8 & 3;
            int js  = jc ^ ((row >> 1) & 3);
            int br = col0 + row;
            const u16* gb = Bm + (size_t)br * K + kt + js * 8;
            __builtin_amdgcn_global_load_lds(
                (const __attribute__((address_space(1))) void*)gb,
                (__attribute__((address_space(3))) void*)(&Bs[b][e8 * 8]), 16, 0, 0);
        }
    };

    f32x4 acc[4][4] = {};

    const int nt = K / 32;
    stage(0, 0);
    if (nt > 1) stage(1, 32);

    const int rl = lane & 15;
    const int qq = lane >> 4;
    for (int t = 0; t < nt; ++t) {
        if (t + 1 < nt) vmwait<3>();
        else            vmwait<0>();
        __builtin_amdgcn_s_barrier();
        asm volatile("" ::: "memory");
        if (t + 2 < nt) stage((t + 2) % 3, (t + 2) * 32);

        const u16* as = As[t % 3];
        const u16* bs = Bs[t % 3];
        bf16x8 af[4], bfr[4];
#pragma unroll
        for (int mi = 0; mi < 4; ++mi) {
            int arow = wm * 64 + mi * 16 + rl;
            int u = qq ^ ((arow >> 1) & 3);
            af[mi] = *(const bf16x8*)&as[arow * 32 + u * 8];
        }
#pragma unroll
        for (int ni = 0; ni < 4; ++ni) {
            int brow = wn * 64 + ni * 16 + rl;
            int u = qq ^ ((brow >> 1) & 3);
            bfr[ni] = *(const bf16x8*)&bs[brow * 32 + u * 8];
        }
#pragma unroll
        for (int mi = 0; mi < 4; ++mi)
#pragma unroll
            for (int ni = 0; ni < 4; ++ni)
                acc[mi][ni] = __builtin_amdgcn_mfma_f32_16x16x32_bf16(
                    af[mi], bfr[ni], acc[mi][ni], 0, 0, 0);
    }

    // ---- epilogue: per-wave LDS transpose, vectorized IO ----
    float bcol[4];
#pragma unroll
    for (int ni = 0; ni < 4; ++ni)
        bcol[ni] = bias[col0 + wn * 64 + ni * 16 + rl];

    __syncthreads();   // all waves done reading the K-loop LDS ring
    float* Csw = reinterpret_cast<float*>(smem + wave * (16 * 68 * 4));
    const int rq = lane >> 4;
#pragma unroll
    for (int mi = 0; mi < 4; ++mi) {
#pragma unroll
        for (int ni = 0; ni < 4; ++ni)
#pragma unroll
            for (int q = 0; q < 4; ++q)
                Csw[(rq*4 + q)*68 + ni*16 + rl] = acc[mi][ni][q] + bcol[ni];
        asm volatile("s_waitcnt lgkmcnt(0)" ::: "memory");  // wave-local transpose
        f32x4 va[4];
#pragma unroll
        for (int j = 0; j < 4; ++j)
            va[j] = *(const f32x4*)&Csw[(lane & 15)*68 + rq*16 + 4*j];
        int gr  = row0 + wm*64 + mi*16 + (lane & 15);
        int gc0 = col0 + wn*64 + rq*16;
        if (gr < M)
            epi_vec<EPI, 16>(va, gr, gc0, outf, outb, zrb, auxb, outRow0);
    }
}

// ============ 512-thread 128x128 kernel (mid levels): 8 waves, BK=32 =========
template<int EPI>
__global__ __launch_bounds__(512) void gemm512(
    const u16* __restrict__ A, int lda, int M, int K,
    const u16* __restrict__ Bm,
    const float* __restrict__ bias,
    float* __restrict__ outf,
    u16*  __restrict__ outb,
    u16*  __restrict__ zrb,
    const u16* __restrict__ auxb,
    int outRow0)
{
    __shared__ __align__(16) char smem[4*128*32*2 * 2];  // 65536 B
    u16 (*As)[128*32] = reinterpret_cast<u16(*)[128*32]>(smem);
    u16 (*Bs)[128*32] = reinterpret_cast<u16(*)[128*32]>(smem + 4*128*32*2);

    const int tid  = threadIdx.x;
    const int lane = tid & 63;
    const int wave = tid >> 6;        // 0..7
    const int wm = wave >> 2;         // 0..1 -> 64-row half
    const int wn = wave & 3;          // 0..3 -> 32-col quarter

    int bx, by;
    {
        const int gx = gridDim.x, gy = gridDim.y;
        int p = blockIdx.y * gx + blockIdx.x;
        if ((gy & 7) == 0) {
            int xcd = p & 7, slot = p >> 3;
            bx = slot % gx;
            by = (slot / gx) * 8 + xcd;
        } else { bx = blockIdx.x; by = blockIdx.y; }
    }
    const int row0 = by * 128;
    const int col0 = bx * 128;

    auto stage = [&](int b, int kt) {
        int e8  = tid;                  // 512 units, 1/thread
        int row = e8 >> 2;              // 0..127
        int jc  = e8 & 3;
        int js  = jc ^ ((row >> 1) & 3);
        int ar = row0 + row; if (ar >= M) ar = M - 1;
        const u16* ga = A + (size_t)ar * lda + kt + js * 8;
        __builtin_amdgcn_global_load_lds(
            (const __attribute__((address_space(1))) void*)ga,
            (__attribute__((address_space(3))) void*)(&As[b][e8 * 8]), 16, 0, 0);
        int br = col0 + row;
        const u16* gb = Bm + (size_t)br * K + kt + js * 8;
        __builtin_amdgcn_global_load_lds(
            (const __attribute__((address_space(1))) void*)gb,
            (__attribute__((address_space(3))) void*)(&Bs[b][e8 * 8]), 16, 0, 0);
    };

    f32x4 acc[4][2] = {};

    const int nt = K / 32;
    stage(0, 0);
    stage(1, 32);

    const int rl = lane & 15;
    const int qq = lane >> 4;
    for (int t = 0; t < nt; ++t) {
        if (t + 2 < nt) {
            stage((t + 2) & 3, (t + 2) * 32);
            vmwait<4>();
        } else if (t + 2 == nt) {
            vmwait<2>();
        } else {
            vmwait<0>();
        }
        __builtin_amdgcn_s_barrier();
        asm volatile("" ::: "memory");

        const u16* as = As[t & 3];
        const u16* bs = Bs[t & 3];
        bf16x8 af[4], bfr[2];
#pragma unroll
        for (int mi = 0; mi < 4; ++mi) {
            int arow = wm * 64 + mi * 16 + rl;
            int u = qq ^ ((arow >> 1) & 3);
            af[mi] = *(const bf16x8*)&as[arow * 32 + u * 8];
        }
#pragma unroll
        for (int ni = 0; ni < 2; ++ni) {
            int brow = wn * 32 + ni * 16 + rl;
            int u = qq ^ ((brow >> 1) & 3);
            bfr[ni] = *(const bf16x8*)&bs[brow * 32 + u * 8];
        }
#pragma unroll
        for (int mi = 0; mi < 4; ++mi)
#pragma unroll
            for (int ni = 0; ni < 2; ++ni)
                acc[mi][ni] = __builtin_amdgcn_mfma_f32_16x16x32_bf16(
                    af[mi], bfr[ni], acc[mi][ni], 0, 0, 0);
    }

    // ---- epilogue: per-wave LDS transpose, vectorized IO ----
    float bcol[2];
#pragma unroll
    for (int ni = 0; ni < 2; ++ni)
        bcol[ni] = bias[col0 + wn * 32 + ni * 16 + rl];

    __syncthreads();
    float* Csw = reinterpret_cast<float*>(smem + wave * (16 * 36 * 4));
    const int rq = lane >> 4;
#pragma unroll
    for (int mi = 0; mi < 4; ++mi) {
#pragma unroll
        for (int ni = 0; ni < 2; ++ni)
#pragma unroll
            for (int q = 0; q < 4; ++q)
                Csw[(rq*4 + q)*36 + ni*16 + rl] = acc[mi][ni][q] + bcol[ni];
        asm volatile("s_waitcnt lgkmcnt(0)" ::: "memory");
        f32x4 va[2];
#pragma unroll
        for (int j = 0; j < 2; ++j)
            va[j] = *(const f32x4*)&Csw[(lane & 15)*36 + rq*8 + 4*j];
        int gr  = row0 + wm*64 + mi*16 + (lane & 15);
        int gc0 = col0 + wn*32 + rq*8;
        if (gr < M)
            epi_vec<EPI, 8>(va, gr, gc0, outf, outb, zrb, auxb, outRow0);
    }
}

// ============ 256-thread 128x128 kernel (small levels) ======================
template<int EPI, int BK>
__global__ __launch_bounds__(256) void gemm_bt(
    const u16* __restrict__ A, int lda, int M, int K,
    const u16* __restrict__ Bm,
    const float* __restrict__ bias,
    float* __restrict__ outf,
    u16*  __restrict__ outb,
    u16*  __restrict__ zrb,
    const u16* __restrict__ auxb,
    int outRow0)
{
    constexpr int UPR = BK / 8;
    constexpr int L   = 2 * (128 * UPR) / 256;

    __shared__ __align__(16) char smem[4*128*BK*2 * 2];
    u16 (*As)[128*BK] = reinterpret_cast<u16(*)[128*BK]>(smem);
    u16 (*Bs)[128*BK] = reinterpret_cast<u16(*)[128*BK]>(smem + 4*128*BK*2);

    const int tid  = threadIdx.x;
    const int lane = tid & 63;
    const int wave = tid >> 6;
    const int wm = wave >> 1, wn = wave & 1;

    int bx, by;
    {
        const int gx = gridDim.x, gy = gridDim.y;
        int p = blockIdx.y * gx + blockIdx.x;
        if ((gy & 7) == 0) {
            int xcd = p & 7, slot = p >> 3;
            bx = slot % gx;
            by = (slot / gx) * 8 + xcd;
        } else { bx = blockIdx.x; by = blockIdx.y; }
    }
    const int row0 = by * 128;
    const int col0 = bx * 128;

    auto stage = [&](int b, int kt) {
#pragma unroll
        for (int j = 0; j < (128 * UPR) / 256; ++j) {
            int e8  = j * 256 + tid;
            int row = e8 / UPR;
            int jc  = e8 % UPR;
            int js  = (BK == 32) ? (jc ^ ((row >> 1) & 3)) : (jc ^ (row & 7));
            int ar = row0 + row; if (ar >= M) ar = M - 1;
            const u16* ga = A + (size_t)ar * lda + kt + js * 8;
            __builtin_amdgcn_global_load_lds(
                (const __attribute__((address_space(1))) void*)ga,
                (__attribute__((address_space(3))) void*)(&As[b][e8 * 8]), 16, 0, 0);
            int br = col0 + row;
            const u16* gb = Bm + (size_t)br * K + kt + js * 8;
            __builtin_amdgcn_global_load_lds(
                (const __attribute__((address_space(1))) void*)gb,
                (__attribute__((address_space(3))) void*)(&Bs[b][e8 * 8]), 16, 0, 0);
        }
    };

    f32x4 acc[4][4] = {};

    const int nt = K / BK;
    stage(0, 0);
    if (nt > 1) stage(1, BK);

    const int rl = lane & 15;
    const int qq = lane >> 4;
    for (int t = 0; t < nt; ++t) {
        if (t + 2 < nt) {
            stage((t + 2) & 3, (t + 2) * BK);
            vmwait<2 * L>();
        } else if (t + 2 == nt) {
            vmwait<L>();
        } else {
            vmwait<0>();
        }
        __builtin_amdgcn_s_barrier();
        asm volatile("" ::: "memory");

        const u16* as = As[t & 3];
        const u16* bs = Bs[t & 3];
#pragma unroll
        for (int ks = 0; ks < BK / 32; ++ks) {
            bf16x8 af[4], bfr[4];
#pragma unroll
            for (int mi = 0; mi < 4; ++mi) {
                int arow = wm * 64 + mi * 16 + rl;
                int u = (BK == 32) ? (qq ^ ((arow >> 1) & 3))
                                   : ((ks * 4 + qq) ^ (arow & 7));
                af[mi] = *(const bf16x8*)&as[arow * BK + u * 8];
            }
#pragma unroll
            for (int ni = 0; ni < 4; ++ni) {
                int brow = wn * 64 + ni * 16 + rl;
                int u = (BK == 32) ? (qq ^ ((brow >> 1) & 3))
                                   : ((ks * 4 + qq) ^ (brow & 7));
                bfr[ni] = *(const bf16x8*)&bs[brow * BK + u * 8];
            }
#pragma unroll
            for (int mi = 0; mi < 4; ++mi)
#pragma unroll
                for (int ni = 0; ni < 4; ++ni)
                    acc[mi][ni] = __builtin_amdgcn_mfma_f32_16x16x32_bf16(
                        af[mi], bfr[ni], acc[mi][ni], 0, 0, 0);
        }
    }

    // ---- epilogue: per-wave LDS transpose, vectorized IO ----
    float bcol[4];
#pragma unroll
    for (int ni = 0; ni < 4; ++ni)
        bcol[ni] = bias[col0 + wn * 64 + ni * 16 + rl];

    __syncthreads();
    float* Csw = reinterpret_cast<float*>(smem + wave * (16 * 68 * 4));
    const int rq = lane >> 4;
#pragma unroll
    for (int mi = 0; mi < 4; ++mi) {
#pragma unroll
        for (int ni = 0; ni < 4; ++ni)
#pragma unroll
            for (int q = 0; q < 4; ++q)
                Csw[(rq*4 + q)*68 + ni*16 + rl] = acc[mi][ni][q] + bcol[ni];
        asm volatile("s_waitcnt lgkmcnt(0)" ::: "memory");
        f32x4 va[4];
#pragma unroll
        for (int j = 0; j < 4; ++j)
            va[j] = *(const f32x4*)&Csw[(lane & 15)*68 + rq*16 + 4*j];
        int gr  = row0 + wm*64 + mi*16 + (lane & 15);
        int gc0 = col0 + wn*64 + rq*16;
        if (gr < M)
            epi_vec<EPI, 16>(va, gr, gc0, outf, outb, zrb, auxb, outRow0);
    }
}

extern "C" void kernel_launch(void* const* d_in, const int* in_sizes, int n_in,
                              void* d_out, int out_size, void* d_ws, size_t ws_size,
                              hipStream_t stream) {
    const float* x     = (const float*)d_in[0];
    const float* Ww    = (const float*)d_in[1];
    const float* Wb    = (const float*)d_in[2];
    const float* Uzr_w = (const float*)d_in[3];
    const float* Uzr_b = (const float*)d_in[4];
    const float* Uh_w  = (const float*)d_in[5];
    const float* Uh_b  = (const float*)d_in[6];
    float* out = (float*)d_out;

    char* ws = (char*)d_ws;
    size_t off = 0;
    u16* hb   = (u16*)(ws + off); off += (size_t)NNODES * H * 2;       // 89.5 MB
    u16* zr   = (u16*)(ws + off); off += (size_t)16384 * 1024 * 2;     // 32 MB (bf16 z+hsum)
    u16* rhxb = (u16*)(ws + off); off += (size_t)16384 * 2048 * 2;     // 64 MB (rh / xb union)
    u16* Wwb  = (u16*)(ws + off); off += (size_t)512 * 512 * 2;
    u16* Uzrb = (u16*)(ws + off); off += (size_t)1024 * 2048 * 2;
    u16* Uhb  = (u16*)(ws + off); off += (size_t)512 * 2048 * 2;

    // 1) convert weights + leaf x to bf16
    cvt_kernel<<<dim3(256), 256, 0, stream>>>(Ww, Wwb, 512 * 512 / 4);
    cvt_kernel<<<dim3(2048), 256, 0, stream>>>(Uzr_w, Uzrb, 1024 * 2048 / 4);
    cvt_kernel<<<dim3(1024), 256, 0, stream>>>(Uh_w, Uhb, 512 * 2048 / 4);
    cvt_kernel<<<dim3(8192), 256, 0, stream>>>(x + (size_t)LEAF0 * H, rhxb,
                                               NLEAF * H / 4);

    // 2) leaf GEMM: h = tanh(x @ Ww^T + Wb) — 256x128 tiles, 16 waves/CU
    gemmw<1><<<dim3(H / 128, NLEAF / 256), 512, 0, stream>>>(
        rhxb, H, NLEAF, H, Wwb, Wb, out, hb, nullptr, nullptr, LEAF0);

    // 3) levels 7..0
    static const int pow4[9] = {1, 4, 16, 64, 256, 1024, 4096, 16384, 65536};
    int starts[10]; starts[0] = 0;
    for (int l = 0; l < 9; ++l) starts[l + 1] = starts[l] + pow4[l];

    for (int l = 7; l >= 0; --l) {
        int s = starts[l], m = pow4[l];
        int cs = 4 * s + 1;  // children rows are contiguous: [cs, cs+4m)
        if (m >= 16384) {
            gemmw<0><<<dim3(1024 / 128, m / 256), 512, 0, stream>>>(
                hb + (size_t)cs * H, 2048, m, 2048, Uzrb, Uzr_b,
                nullptr, rhxb, zr, hb + (size_t)cs * H, 0);
            gemmw<2><<<dim3(H / 128, m / 256), 512, 0, stream>>>(
                rhxb, 2048, m, 2048, Uhb, Uh_b,
                out, hb, zr, nullptr, s);
        } else if (m >= 4096) {
            int gm = (m + 127) / 128;
            gemm512<0><<<dim3(1024 / 128, gm), 512, 0, stream>>>(
                hb + (size_t)cs * H, 2048, m, 2048, Uzrb, Uzr_b,
                nullptr, rhxb, zr, hb + (size_t)cs * H, 0);
            gemm512<2><<<dim3(H / 128, gm), 512, 0, stream>>>(
                rhxb, 2048, m, 2048, Uhb, Uh_b,
                out, hb, zr, nullptr, s);
        } else {
            int gm = (m + 127) / 128;
            gemm_bt<0, 64><<<dim3(1024 / 128, gm), 256, 0, stream>>>(
                hb + (size_t)cs * H, 2048, m, 2048, Uzrb, Uzr_b,
                nullptr, rhxb, zr, hb + (size_t)cs * H, 0);
            gemm_bt<2, 64><<<dim3(H / 128, gm), 256, 0, stream>>>(
                rhxb, 2048, m, 2048, Uhb, Uh_b,
                out, hb, zr, nullptr, s);
        }
    }
}

// Round 4
// 646.133 us; speedup vs baseline: 1.6047x; 1.0032x over previous
//
#include <hip/hip_runtime.h>
#include <math.h>

#define H 512
typedef unsigned short u16;
typedef __attribute__((ext_vector_type(8))) short bf16x8;
typedef __attribute__((ext_vector_type(4))) float f32x4;
typedef __attribute__((ext_vector_type(8))) unsigned short u16x8;

constexpr int LEAF0  = 21845;   // starts[8]
constexpr int NLEAF  = 65536;
constexpr int NNODES = 87381;

__device__ __forceinline__ u16 f2b(float f) {
    union { float f; unsigned u; } v; v.f = f;
    unsigned r = v.u + 0x7fffu + ((v.u >> 16) & 1u);  // RNE
    return (u16)(r >> 16);
}
__device__ __forceinline__ float b2f(u16 b) {
    union { unsigned u; float f; } v; v.u = ((unsigned)b) << 16; return v.f;
}
__device__ __forceinline__ float sigm(float x) {
    return __fdividef(1.f, 1.f + __expf(-x));
}
__device__ __forceinline__ float ftanh(float x) {
    float e = __expf(-2.f * fabsf(x));
    float r = __fdividef(1.f - e, 1.f + e);
    return copysignf(r, x);
}

template<int N> __device__ __forceinline__ void vmwait() {
    if constexpr (N == 0)       asm volatile("s_waitcnt vmcnt(0)" ::: "memory");
    else if constexpr (N == 2)  asm volatile("s_waitcnt vmcnt(2)" ::: "memory");
    else if constexpr (N == 3)  asm volatile("s_waitcnt vmcnt(3)" ::: "memory");
    else if constexpr (N == 4)  asm volatile("s_waitcnt vmcnt(4)" ::: "memory");
    else if constexpr (N == 6)  asm volatile("s_waitcnt vmcnt(6)" ::: "memory");
    else if constexpr (N == 8)  asm volatile("s_waitcnt vmcnt(8)" ::: "memory");
    else                        asm volatile("s_waitcnt vmcnt(16)" ::: "memory");
}

// ---------------- vectorized fused epilogue (per-lane, NC contiguous cols) --
// va: NC/4 f32x4 of pre-bias-added GEMM outputs for row gr, cols [gc0,gc0+NC)
// EPI0 aux reads come from a per-wave LDS slice (64 child rows x WC cols,
// XOR-swizzled in 16B units: slot = seg ^ ((row>>2)&(WC/8-1))), staged by the
// caller via global_load_lds with pre-swizzled global source. Bit-identical
// arithmetic (same bf16 bits, ch 0..3 summation order).
template<int EPI, int NC, int WC>
__device__ __forceinline__ void epi_vec(
    const f32x4* va, int gr, int gc0,
    float* __restrict__ outf, u16* __restrict__ outb,
    u16* __restrict__ zrb, const u16* auxl, int lrow, int coffs, int outRow0)
{
    constexpr int NV = NC / 8;
    if constexpr (EPI == 1) {
        f32x4 ov[NC/4]; u16x8 hv[NV];
#pragma unroll
        for (int i = 0; i < NC; ++i) {
            float v = ftanh(va[i>>2][i&3]);
            ov[i>>2][i&3] = v; hv[i>>3][i&7] = f2b(v);
        }
        size_t o = (size_t)(outRow0 + gr) * H + gc0;
#pragma unroll
        for (int j = 0; j < NC/4; ++j) *(f32x4*)&outf[o + 4*j] = ov[j];
#pragma unroll
        for (int j = 0; j < NV; ++j) *(u16x8*)&outb[o + 8*j] = hv[j];
    } else if constexpr (EPI == 0) {
        auto aux_read = [&](int ch, int jj) -> u16x8 {
            int cr  = 4*lrow + ch;
            int key = (cr >> 2) & (WC/8 - 1);
            int j   = (coffs >> 3) + jj;
            return *(const u16x8*)&auxl[cr*WC + ((j ^ key) << 3)];
        };
        if (gc0 < H) {
            u16x8 zv[NV]; f32x4 hs[NC/4];
#pragma unroll
            for (int i = 0; i < NC; ++i) {
                zv[i>>3][i&7] = f2b(sigm(va[i>>2][i&3]));
                hs[i>>2][i&3] = 0.f;
            }
#pragma unroll
            for (int ch = 0; ch < 4; ++ch) {
#pragma unroll
                for (int j = 0; j < NV; ++j) {
                    u16x8 cv = aux_read(ch, j);
#pragma unroll
                    for (int k = 0; k < 8; ++k) {
                        int i = 8*j + k;
                        hs[i>>2][i&3] += b2f(cv[k]);
                    }
                }
            }
            u16x8 sv[NV];
#pragma unroll
            for (int i = 0; i < NC; ++i) sv[i>>3][i&7] = f2b(hs[i>>2][i&3]);
            size_t zo = (size_t)gr * 1024 + gc0;
#pragma unroll
            for (int j = 0; j < NV; ++j) *(u16x8*)&zrb[zo + 8*j] = zv[j];
#pragma unroll
            for (int j = 0; j < NV; ++j) *(u16x8*)&zrb[zo + H + 8*j] = sv[j];
        } else {
            f32x4 rr[NC/4];
#pragma unroll
            for (int i = 0; i < NC; ++i) rr[i>>2][i&3] = sigm(va[i>>2][i&3]);
            const int cc = gc0 - H;
#pragma unroll
            for (int ch = 0; ch < 4; ++ch) {
#pragma unroll
                for (int j = 0; j < NV; ++j) {
                    u16x8 cv = aux_read(ch, j);
                    u16x8 ov;
#pragma unroll
                    for (int k = 0; k < 8; ++k) {
                        int i = 8*j + k;
                        ov[k] = f2b(rr[i>>2][i&3] * b2f(cv[k]));
                    }
                    *(u16x8*)&outb[(size_t)gr*2048 + ch*H + cc + 8*j] = ov;
                }
            }
        }
    } else { // EPI == 2
        size_t zo = (size_t)gr * 1024 + gc0;
        u16x8 zv[NV], sv[NV];
#pragma unroll
        for (int j = 0; j < NV; ++j) zv[j] = *(const u16x8*)&zrb[zo + 8*j];
#pragma unroll
        for (int j = 0; j < NV; ++j) sv[j] = *(const u16x8*)&zrb[zo + H + 8*j];
        f32x4 ov[NC/4]; u16x8 hv[NV];
#pragma unroll
        for (int i = 0; i < NC; ++i) {
            float hc = ftanh(va[i>>2][i&3]);
            float z  = b2f(zv[i>>3][i&7]);
            float v  = b2f(sv[i>>3][i&7]) * z + (1.f - z) * hc;
            ov[i>>2][i&3] = v; hv[i>>3][i&7] = f2b(v);
        }
        size_t o = (size_t)(outRow0 + gr) * H + gc0;
#pragma unroll
        for (int j = 0; j < NC/4; ++j) *(f32x4*)&outf[o + 4*j] = ov[j];
#pragma unroll
        for (int j = 0; j < NV; ++j) *(u16x8*)&outb[o + 8*j] = hv[j];
    }
}

// ---- EPI0 aux slice staging: 64 child rows x WC cols into per-wave LDS ----
// Linear LDS dest (global_load_lds), pre-swizzled global source seg:
// content at slot s' of row r = global seg s' ^ ((r>>2)&(WC/8-1)).
template<int WC>
__device__ __forceinline__ void stage_aux(
    u16* wls, const u16* auxg, int lane)
{
    constexpr int UPW = WC / 8;          // 16B units per row
    constexpr int NIT = 64 * UPW / 64;   // instructions per wave
#pragma unroll
    for (int it = 0; it < NIT; ++it) {
        int row = (it * 64 + lane) / UPW;
        int sp  = (lane & (UPW - 1)) ^ ((row >> 2) & (UPW - 1));
        const u16* ga = auxg + row * H + sp * 8;
        __builtin_amdgcn_global_load_lds(
            (const __attribute__((address_space(1))) void*)ga,
            (__attribute__((address_space(3))) void*)(&wls[it * 512]), 16, 0, 0);
    }
}

// ---------------- fp32 -> bf16 conversion (all tensors, one launch) --------
__global__ void cvt_all(const float* __restrict__ s0, u16* __restrict__ d0, int n0,
                        const float* __restrict__ s1, u16* __restrict__ d1, int n1,
                        const float* __restrict__ s2, u16* __restrict__ d2, int n2,
                        const float* __restrict__ s3, u16* __restrict__ d3, int n3)
{
    int i = blockIdx.x * blockDim.x + threadIdx.x;
    int st = gridDim.x * blockDim.x;
    int tot = n0 + n1 + n2 + n3;
    for (; i < tot; i += st) {
        const float* s; u16* d; int k = i;
        if (k < n0)      { s = s0; d = d0; }
        else { k -= n0;
        if (k < n1)      { s = s1; d = d1; }
        else { k -= n1;
        if (k < n2)      { s = s2; d = d2; }
        else { k -= n2;    s = s3; d = d3; } } }
        float4 v = ((const float4*)s)[k];
        ushort4 o;
        o.x = f2b(v.x); o.y = f2b(v.y); o.z = f2b(v.z); o.w = f2b(v.w);
        ((ushort4*)d)[k] = o;
    }
}

// ============ 512-thread 256x128 kernel (big levels): 16 waves/CU ===========
// K-loop unchanged (audited): NBUF=3 ring, depth-2 prefetch, counted vmcnt
// (3/0), ONE barrier/iter, stage(t+2) after the barrier.
// Epilogue: per-wave LDS transpose + (EPI0) coalesced aux LDS restage.
template<int EPI>
__global__ __launch_bounds__(512, 4) void gemmw(
    const u16* __restrict__ A, int lda, int M, int K,
    const u16* __restrict__ Bm,
    const float* __restrict__ bias,
    float* __restrict__ outf,
    u16*  __restrict__ outb,
    u16*  __restrict__ zrb,
    const u16* __restrict__ auxb,
    int outRow0)
{
    __shared__ __align__(16) char smem[3*256*32*2 + 3*128*32*2]; // 73728 B
    u16 (*As)[256*32] = reinterpret_cast<u16(*)[256*32]>(smem);
    u16 (*Bs)[128*32] = reinterpret_cast<u16(*)[128*32]>(smem + 3*256*32*2);

    const int tid  = threadIdx.x;
    const int lane = tid & 63;
    const int wave = tid >> 6;        // 0..7
    const int wm = wave >> 1;         // 0..3 -> 64-row band of 256
    const int wn = wave & 1;          // 0..1 -> 64-col half of 128

    int bx, by;
    {
        const int gx = gridDim.x, gy = gridDim.y;
        int p = blockIdx.y * gx + blockIdx.x;
        if ((gy & 7) == 0) {
            int xcd = p & 7, slot = p >> 3;
            bx = slot % gx;
            by = (slot / gx) * 8 + xcd;
        } else { bx = blockIdx.x; by = blockIdx.y; }
    }
    const int row0 = by * 256;
    const int col0 = bx * 128;

    auto stage = [&](int b, int kt) {
#pragma unroll
        for (int j = 0; j < 2; ++j) {
            int e8  = j * 512 + tid;
            int row = e8 >> 2;              // 0..255
            int jc  = e8 & 3;
            int js  = jc ^ ((row >> 1) & 3);
            int ar = row0 + row; if (ar >= M) ar = M - 1;
            const u16* ga = A + (size_t)ar * lda + kt + js * 8;
            __builtin_amdgcn_global_load_lds(
                (const __attribute__((address_space(1))) void*)ga,
                (__attribute__((address_space(3))) void*)(&As[b][e8 * 8]), 16, 0, 0);
        }
        {
            int e8  = tid;
            int row = e8 >> 2;              // 0..127
            int jc  = e8 & 3;
            int js  = jc ^ ((row >> 1) & 3);
            int br = col0 + row;
            const u16* gb = Bm + (size_t)br * K + kt + js * 8;
            __builtin_amdgcn_global_load_lds(
                (const __attribute__((address_space(1))) void*)gb,
                (__attribute__((address_space(3))) void*)(&Bs[b][e8 * 8]), 16, 0, 0);
        }
    };

    f32x4 acc[4][4] = {};

    const int nt = K / 32;
    stage(0, 0);
    if (nt > 1) stage(1, 32);

    const int rl = lane & 15;
    const int qq = lane >> 4;
    for (int t = 0; t < nt; ++t) {
        if (t + 1 < nt) vmwait<3>();
        else            vmwait<0>();
        __builtin_amdgcn_s_barrier();
        asm volatile("" ::: "memory");
        if (t + 2 < nt) stage((t + 2) % 3, (t + 2) * 32);

        const u16* as = As[t % 3];
        const u16* bs = Bs[t % 3];
        bf16x8 af[4], bfr[4];
#pragma unroll
        for (int mi = 0; mi < 4; ++mi) {
            int arow = wm * 64 + mi * 16 + rl;
            int u = qq ^ ((arow >> 1) & 3);
            af[mi] = *(const bf16x8*)&as[arow * 32 + u * 8];
        }
#pragma unroll
        for (int ni = 0; ni < 4; ++ni) {
            int brow = wn * 64 + ni * 16 + rl;
            int u = qq ^ ((brow >> 1) & 3);
            bfr[ni] = *(const bf16x8*)&bs[brow * 32 + u * 8];
        }
#pragma unroll
        for (int mi = 0; mi < 4; ++mi)
#pragma unroll
            for (int ni = 0; ni < 4; ++ni)
                acc[mi][ni] = __builtin_amdgcn_mfma_f32_16x16x32_bf16(
                    af[mi], bfr[ni], acc[mi][ni], 0, 0, 0);
    }

    // ---- epilogue ----
    float bcol[4];
#pragma unroll
    for (int ni = 0; ni < 4; ++ni)
        bcol[ni] = bias[col0 + wn * 64 + ni * 16 + rl];

    __syncthreads();   // all waves done reading the K-loop LDS ring
    char* wreg = smem + wave * 8192;            // per-wave region (8 KB)
    float* Csw = reinterpret_cast<float*>(wreg);
    u16*   wls = reinterpret_cast<u16*>(wreg);
    const int rq  = lane >> 4;
    const int rl2 = lane & 15;
#pragma unroll
    for (int mi = 0; mi < 4; ++mi) {
#pragma unroll
        for (int ni = 0; ni < 4; ++ni)
#pragma unroll
            for (int q = 0; q < 4; ++q)
                Csw[(rq*4 + q)*68 + ni*16 + rl2] = acc[mi][ni][q] + bcol[ni];
        asm volatile("s_waitcnt lgkmcnt(0)" ::: "memory");  // wave-local transpose
        f32x4 va[4];
#pragma unroll
        for (int j = 0; j < 4; ++j)
            va[j] = *(const f32x4*)&Csw[rl2*68 + rq*16 + 4*j];
        if constexpr (EPI == 0) {
            asm volatile("s_waitcnt lgkmcnt(0)" ::: "memory"); // va reads done
            int c0 = ((col0 < H) ? col0 : col0 - H) + wn * 64;
            const u16* auxg = auxb + (size_t)(4*(row0 + wm*64 + mi*16)) * H + c0;
            stage_aux<64>(wls, auxg, lane);
            vmwait<0>();
        }
        int gr  = row0 + wm*64 + mi*16 + rl2;
        int gc0 = col0 + wn*64 + rq*16;
        if (gr < M)
            epi_vec<EPI, 16, 64>(va, gr, gc0, outf, outb, zrb, wls, rl2, rq*16, outRow0);
    }
}

// ============ 512-thread 128x128 kernel (mid levels): 8 waves, BK=32 =========
template<int EPI>
__global__ __launch_bounds__(512) void gemm512(
    const u16* __restrict__ A, int lda, int M, int K,
    const u16* __restrict__ Bm,
    const float* __restrict__ bias,
    float* __restrict__ outf,
    u16*  __restrict__ outb,
    u16*  __restrict__ zrb,
    const u16* __restrict__ auxb,
    int outRow0)
{
    __shared__ __align__(16) char smem[4*128*32*2 * 2];  // 65536 B
    u16 (*As)[128*32] = reinterpret_cast<u16(*)[128*32]>(smem);
    u16 (*Bs)[128*32] = reinterpret_cast<u16(*)[128*32]>(smem + 4*128*32*2);

    const int tid  = threadIdx.x;
    const int lane = tid & 63;
    const int wave = tid >> 6;        // 0..7
    const int wm = wave >> 2;         // 0..1 -> 64-row half
    const int wn = wave & 3;          // 0..3 -> 32-col quarter

    int bx, by;
    {
        const int gx = gridDim.x, gy = gridDim.y;
        int p = blockIdx.y * gx + blockIdx.x;
        if ((gy & 7) == 0) {
            int xcd = p & 7, slot = p >> 3;
            bx = slot % gx;
            by = (slot / gx) * 8 + xcd;
        } else { bx = blockIdx.x; by = blockIdx.y; }
    }
    const int row0 = by * 128;
    const int col0 = bx * 128;

    auto stage = [&](int b, int kt) {
        int e8  = tid;                  // 512 units, 1/thread
        int row = e8 >> 2;              // 0..127
        int jc  = e8 & 3;
        int js  = jc ^ ((row >> 1) & 3);
        int ar = row0 + row; if (ar >= M) ar = M - 1;
        const u16* ga = A + (size_t)ar * lda + kt + js * 8;
        __builtin_amdgcn_global_load_lds(
            (const __attribute__((address_space(1))) void*)ga,
            (__attribute__((address_space(3))) void*)(&As[b][e8 * 8]), 16, 0, 0);
        int br = col0 + row;
        const u16* gb = Bm + (size_t)br * K + kt + js * 8;
        __builtin_amdgcn_global_load_lds(
            (const __attribute__((address_space(1))) void*)gb,
            (__attribute__((address_space(3))) void*)(&Bs[b][e8 * 8]), 16, 0, 0);
    };

    f32x4 acc[4][2] = {};

    const int nt = K / 32;
    stage(0, 0);
    stage(1, 32);

    const int rl = lane & 15;
    const int qq = lane >> 4;
    for (int t = 0; t < nt; ++t) {
        if (t + 2 < nt) {
            stage((t + 2) & 3, (t + 2) * 32);
            vmwait<4>();
        } else if (t + 2 == nt) {
            vmwait<2>();
        } else {
            vmwait<0>();
        }
        __builtin_amdgcn_s_barrier();
        asm volatile("" ::: "memory");

        const u16* as = As[t & 3];
        const u16* bs = Bs[t & 3];
        bf16x8 af[4], bfr[2];
#pragma unroll
        for (int mi = 0; mi < 4; ++mi) {
            int arow = wm * 64 + mi * 16 + rl;
            int u = qq ^ ((arow >> 1) & 3);
            af[mi] = *(const bf16x8*)&as[arow * 32 + u * 8];
        }
#pragma unroll
        for (int ni = 0; ni < 2; ++ni) {
            int brow = wn * 32 + ni * 16 + rl;
            int u = qq ^ ((brow >> 1) & 3);
            bfr[ni] = *(const bf16x8*)&bs[brow * 32 + u * 8];
        }
#pragma unroll
        for (int mi = 0; mi < 4; ++mi)
#pragma unroll
            for (int ni = 0; ni < 2; ++ni)
                acc[mi][ni] = __builtin_amdgcn_mfma_f32_16x16x32_bf16(
                    af[mi], bfr[ni], acc[mi][ni], 0, 0, 0);
    }

    // ---- epilogue ----
    float bcol[2];
#pragma unroll
    for (int ni = 0; ni < 2; ++ni)
        bcol[ni] = bias[col0 + wn * 32 + ni * 16 + rl];

    __syncthreads();
    char* wreg = smem + wave * 8192;
    float* Csw = reinterpret_cast<float*>(wreg);
    u16*   wls = reinterpret_cast<u16*>(wreg);
    const int rq  = lane >> 4;
    const int rl2 = lane & 15;
#pragma unroll
    for (int mi = 0; mi < 4; ++mi) {
#pragma unroll
        for (int ni = 0; ni < 2; ++ni)
#pragma unroll
            for (int q = 0; q < 4; ++q)
                Csw[(rq*4 + q)*36 + ni*16 + rl2] = acc[mi][ni][q] + bcol[ni];
        asm volatile("s_waitcnt lgkmcnt(0)" ::: "memory");
        f32x4 va[2];
#pragma unroll
        for (int j = 0; j < 2; ++j)
            va[j] = *(const f32x4*)&Csw[rl2*36 + rq*8 + 4*j];
        if constexpr (EPI == 0) {
            asm volatile("s_waitcnt lgkmcnt(0)" ::: "memory");
            int c0 = ((col0 < H) ? col0 : col0 - H) + wn * 32;
            const u16* auxg = auxb + (size_t)(4*(row0 + wm*64 + mi*16)) * H + c0;
            stage_aux<32>(wls, auxg, lane);
            vmwait<0>();
        }
        int gr  = row0 + wm*64 + mi*16 + rl2;
        int gc0 = col0 + wn*32 + rq*8;
        if (gr < M)
            epi_vec<EPI, 8, 32>(va, gr, gc0, outf, outb, zrb, wls, rl2, rq*8, outRow0);
    }
}

// ============ 256-thread 128x128 kernel (small levels) ======================
template<int EPI, int BK>
__global__ __launch_bounds__(256) void gemm_bt(
    const u16* __restrict__ A, int lda, int M, int K,
    const u16* __restrict__ Bm,
    const float* __restrict__ bias,
    float* __restrict__ outf,
    u16*  __restrict__ outb,
    u16*  __restrict__ zrb,
    const u16* __restrict__ auxb,
    int outRow0)
{
    constexpr int UPR = BK / 8;
    constexpr int L   = 2 * (128 * UPR) / 256;

    __shared__ __align__(16) char smem[4*128*BK*2 * 2];
    u16 (*As)[128*BK] = reinterpret_cast<u16(*)[128*BK]>(smem);
    u16 (*Bs)[128*BK] = reinterpret_cast<u16(*)[128*BK]>(smem + 4*128*BK*2);

    const int tid  = threadIdx.x;
    const int lane = tid & 63;
    const int wave = tid >> 6;
    const int wm = wave >> 1, wn = wave & 1;

    int bx, by;
    {
        const int gx = gridDim.x, gy = gridDim.y;
        int p = blockIdx.y * gx + blockIdx.x;
        if ((gy & 7) == 0) {
            int xcd = p & 7, slot = p >> 3;
            bx = slot % gx;
            by = (slot / gx) * 8 + xcd;
        } else { bx = blockIdx.x; by = blockIdx.y; }
    }
    const int row0 = by * 128;
    const int col0 = bx * 128;

    auto stage = [&](int b, int kt) {
#pragma unroll
        for (int j = 0; j < (128 * UPR) / 256; ++j) {
            int e8  = j * 256 + tid;
            int row = e8 / UPR;
            int jc  = e8 % UPR;
            int js  = (BK == 32) ? (jc ^ ((row >> 1) & 3)) : (jc ^ (row & 7));
            int ar = row0 + row; if (ar >= M) ar = M - 1;
            const u16* ga = A + (size_t)ar * lda + kt + js * 8;
            __builtin_amdgcn_global_load_lds(
                (const __attribute__((address_space(1))) void*)ga,
                (__attribute__((address_space(3))) void*)(&As[b][e8 * 8]), 16, 0, 0);
            int br = col0 + row;
            const u16* gb = Bm + (size_t)br * K + kt + js * 8;
            __builtin_amdgcn_global_load_lds(
                (const __attribute__((address_space(1))) void*)gb,
                (__attribute__((address_space(3))) void*)(&Bs[b][e8 * 8]), 16, 0, 0);
        }
    };

    f32x4 acc[4][4] = {};

    const int nt = K / BK;
    stage(0, 0);
    if (nt > 1) stage(1, BK);

    const int rl = lane & 15;
    const int qq = lane >> 4;
    for (int t = 0; t < nt; ++t) {
        if (t + 2 < nt) {
            stage((t + 2) & 3, (t + 2) * BK);
            vmwait<2 * L>();
        } else if (t + 2 == nt) {
            vmwait<L>();
        } else {
            vmwait<0>();
        }
        __builtin_amdgcn_s_barrier();
        asm volatile("" ::: "memory");

        const u16* as = As[t & 3];
        const u16* bs = Bs[t & 3];
#pragma unroll
        for (int ks = 0; ks < BK / 32; ++ks) {
            bf16x8 af[4], bfr[4];
#pragma unroll
            for (int mi = 0; mi < 4; ++mi) {
                int arow = wm * 64 + mi * 16 + rl;
                int u = (BK == 32) ? (qq ^ ((arow >> 1) & 3))
                                   : ((ks * 4 + qq) ^ (arow & 7));
                af[mi] = *(const bf16x8*)&as[arow * BK + u * 8];
            }
#pragma unroll
            for (int ni = 0; ni < 4; ++ni) {
                int brow = wn * 64 + ni * 16 + rl;
                int u = (BK == 32) ? (qq ^ ((brow >> 1) & 3))
                                   : ((ks * 4 + qq) ^ (brow & 7));
                bfr[ni] = *(const bf16x8*)&bs[brow * BK + u * 8];
            }
#pragma unroll
            for (int mi = 0; mi < 4; ++mi)
#pragma unroll
                for (int ni = 0; ni < 4; ++ni)
                    acc[mi][ni] = __builtin_amdgcn_mfma_f32_16x16x32_bf16(
                        af[mi], bfr[ni], acc[mi][ni], 0, 0, 0);
        }
    }

    // ---- epilogue ----
    float bcol[4];
#pragma unroll
    for (int ni = 0; ni < 4; ++ni)
        bcol[ni] = bias[col0 + wn * 64 + ni * 16 + rl];

    __syncthreads();
    char* wreg = smem + wave * 8192;
    float* Csw = reinterpret_cast<float*>(wreg);
    u16*   wls = reinterpret_cast<u16*>(wreg);
    const int rq  = lane >> 4;
    const int rl2 = lane & 15;
#pragma unroll
    for (int mi = 0; mi < 4; ++mi) {
#pragma unroll
        for (int ni = 0; ni < 4; ++ni)
#pragma unroll
            for (int q = 0; q < 4; ++q)
                Csw[(rq*4 + q)*68 + ni*16 + rl2] = acc[mi][ni][q] + bcol[ni];
        asm volatile("s_waitcnt lgkmcnt(0)" ::: "memory");
        f32x4 va[4];
#pragma unroll
        for (int j = 0; j < 4; ++j)
            va[j] = *(const f32x4*)&Csw[rl2*68 + rq*16 + 4*j];
        if constexpr (EPI == 0) {
            asm volatile("s_waitcnt lgkmcnt(0)" ::: "memory");
            int c0 = ((col0 < H) ? col0 : col0 - H) + wn * 64;
            const u16* auxg = auxb + (size_t)(4*(row0 + wm*64 + mi*16)) * H + c0;
            stage_aux<64>(wls, auxg, lane);
            vmwait<0>();
        }
        int gr  = row0 + wm*64 + mi*16 + rl2;
        int gc0 = col0 + wn*64 + rq*16;
        if (gr < M)
            epi_vec<EPI, 16, 64>(va, gr, gc0, outf, outb, zrb, wls, rl2, rq*16, outRow0);
    }
}

extern "C" void kernel_launch(void* const* d_in, const int* in_sizes, int n_in,
                              void* d_out, int out_size, void* d_ws, size_t ws_size,
                              hipStream_t stream) {
    const float* x     = (const float*)d_in[0];
    const float* Ww    = (const float*)d_in[1];
    const float* Wb    = (const float*)d_in[2];
    const float* Uzr_w = (const float*)d_in[3];
    const float* Uzr_b = (const float*)d_in[4];
    const float* Uh_w  = (const float*)d_in[5];
    const float* Uh_b  = (const float*)d_in[6];
    float* out = (float*)d_out;

    char* ws = (char*)d_ws;
    size_t off = 0;
    u16* hb   = (u16*)(ws + off); off += (size_t)NNODES * H * 2;       // 89.5 MB
    u16* zr   = (u16*)(ws + off); off += (size_t)16384 * 1024 * 2;     // 32 MB (bf16 z+hsum)
    u16* rhxb = (u16*)(ws + off); off += (size_t)16384 * 2048 * 2;     // 64 MB (rh / xb union)
    u16* Wwb  = (u16*)(ws + off); off += (size_t)512 * 512 * 2;
    u16* Uzrb = (u16*)(ws + off); off += (size_t)1024 * 2048 * 2;
    u16* Uhb  = (u16*)(ws + off); off += (size_t)512 * 2048 * 2;

    // 1) convert weights + leaf x to bf16 (single launch)
    cvt_all<<<dim3(8192), 256, 0, stream>>>(
        Ww, Wwb, 512 * 512 / 4,
        Uzr_w, Uzrb, 1024 * 2048 / 4,
        Uh_w, Uhb, 512 * 2048 / 4,
        x + (size_t)LEAF0 * H, rhxb, NLEAF * H / 4);

    // 2) leaf GEMM: h = tanh(x @ Ww^T + Wb) — 256x128 tiles, 16 waves/CU
    gemmw<1><<<dim3(H / 128, NLEAF / 256), 512, 0, stream>>>(
        rhxb, H, NLEAF, H, Wwb, Wb, out, hb, nullptr, nullptr, LEAF0);

    // 3) levels 7..0
    static const int pow4[9] = {1, 4, 16, 64, 256, 1024, 4096, 16384, 65536};
    int starts[10]; starts[0] = 0;
    for (int l = 0; l < 9; ++l) starts[l + 1] = starts[l] + pow4[l];

    for (int l = 7; l >= 0; --l) {
        int s = starts[l], m = pow4[l];
        int cs = 4 * s + 1;  // children rows are contiguous: [cs, cs+4m)
        if (m >= 16384) {
            gemmw<0><<<dim3(1024 / 128, m / 256), 512, 0, stream>>>(
                hb + (size_t)cs * H, 2048, m, 2048, Uzrb, Uzr_b,
                nullptr, rhxb, zr, hb + (size_t)cs * H, 0);
            gemmw<2><<<dim3(H / 128, m / 256), 512, 0, stream>>>(
                rhxb, 2048, m, 2048, Uhb, Uh_b,
                out, hb, zr, nullptr, s);
        } else if (m >= 4096) {
            int gm = (m + 127) / 128;
            gemm512<0><<<dim3(1024 / 128, gm), 512, 0, stream>>>(
                hb + (size_t)cs * H, 2048, m, 2048, Uzrb, Uzr_b,
                nullptr, rhxb, zr, hb + (size_t)cs * H, 0);
            gemm512<2><<<dim3(H / 128, gm), 512, 0, stream>>>(
                rhxb, 2048, m, 2048, Uhb, Uh_b,
                out, hb, zr, nullptr, s);
        } else {
            int gm = (m + 127) / 128;
            gemm_bt<0, 64><<<dim3(1024 / 128, gm), 256, 0, stream>>>(
                hb + (size_t)cs * H, 2048, m, 2048, Uzrb, Uzr_b,
                nullptr, rhxb, zr, hb + (size_t)cs * H, 0);
            gemm_bt<2, 64><<<dim3(H / 128, gm), 256, 0, stream>>>(
                rhxb, 2048, m, 2048, Uhb, Uh_b,
                out, hb, zr, nullptr, s);
        }
    }
}

// Round 5
// 644.823 us; speedup vs baseline: 1.6080x; 1.0020x over previous
//
#include <hip/hip_runtime.h>
#include <math.h>

#define H 512
typedef unsigned short u16;
typedef __attribute__((ext_vector_type(8))) short bf16x8;
typedef __attribute__((ext_vector_type(4))) float f32x4;
typedef __attribute__((ext_vector_type(8))) unsigned short u16x8;

constexpr int LEAF0  = 21845;   // starts[8]
constexpr int NLEAF  = 65536;
constexpr int NNODES = 87381;

__device__ __forceinline__ u16 f2b(float f) {
    union { float f; unsigned u; } v; v.f = f;
    unsigned r = v.u + 0x7fffu + ((v.u >> 16) & 1u);  // RNE
    return (u16)(r >> 16);
}
__device__ __forceinline__ float b2f(u16 b) {
    union { unsigned u; float f; } v; v.u = ((unsigned)b) << 16; return v.f;
}
__device__ __forceinline__ float sigm(float x) {
    return __fdividef(1.f, 1.f + __expf(-x));
}
__device__ __forceinline__ float ftanh(float x) {
    float e = __expf(-2.f * fabsf(x));
    float r = __fdividef(1.f - e, 1.f + e);
    return copysignf(r, x);
}

template<int N> __device__ __forceinline__ void vmwait() {
    if constexpr (N == 0)       asm volatile("s_waitcnt vmcnt(0)" ::: "memory");
    else if constexpr (N == 2)  asm volatile("s_waitcnt vmcnt(2)" ::: "memory");
    else if constexpr (N == 3)  asm volatile("s_waitcnt vmcnt(3)" ::: "memory");
    else if constexpr (N == 4)  asm volatile("s_waitcnt vmcnt(4)" ::: "memory");
    else if constexpr (N == 6)  asm volatile("s_waitcnt vmcnt(6)" ::: "memory");
    else if constexpr (N == 8)  asm volatile("s_waitcnt vmcnt(8)" ::: "memory");
    else                        asm volatile("s_waitcnt vmcnt(16)" ::: "memory");
}

__device__ __forceinline__ void gload16(const u16* g, u16* l) {
    __builtin_amdgcn_global_load_lds(
        (const __attribute__((address_space(1))) void*)g,
        (__attribute__((address_space(3))) void*)l, 16, 0, 0);
}

// ---------------- vectorized fused epilogue (per-lane, NC contiguous cols) --
// va: NC/4 f32x4 of pre-bias-added GEMM outputs for row gr, cols [gc0,gc0+NC)
// EPI0 aux reads come from a per-wave LDS slice (64 child rows x WC cols,
// XOR-swizzled in 16B units). Bit-identical arithmetic to the scalar version.
template<int EPI, int NC, int WC>
__device__ __forceinline__ void epi_vec(
    const f32x4* va, int gr, int gc0,
    float* __restrict__ outf, u16* __restrict__ outb,
    u16* __restrict__ zrb, const u16* auxl, int lrow, int coffs, int outRow0)
{
    constexpr int NV = NC / 8;
    if constexpr (EPI == 1) {
        f32x4 ov[NC/4]; u16x8 hv[NV];
#pragma unroll
        for (int i = 0; i < NC; ++i) {
            float v = ftanh(va[i>>2][i&3]);
            ov[i>>2][i&3] = v; hv[i>>3][i&7] = f2b(v);
        }
        size_t o = (size_t)(outRow0 + gr) * H + gc0;
#pragma unroll
        for (int j = 0; j < NC/4; ++j) *(f32x4*)&outf[o + 4*j] = ov[j];
#pragma unroll
        for (int j = 0; j < NV; ++j) *(u16x8*)&outb[o + 8*j] = hv[j];
    } else if constexpr (EPI == 0) {
        auto aux_read = [&](int ch, int jj) -> u16x8 {
            int cr  = 4*lrow + ch;
            int key = (cr >> 2) & (WC/8 - 1);
            int j   = (coffs >> 3) + jj;
            return *(const u16x8*)&auxl[cr*WC + ((j ^ key) << 3)];
        };
        if (gc0 < H) {
            u16x8 zv[NV]; f32x4 hs[NC/4];
#pragma unroll
            for (int i = 0; i < NC; ++i) {
                zv[i>>3][i&7] = f2b(sigm(va[i>>2][i&3]));
                hs[i>>2][i&3] = 0.f;
            }
#pragma unroll
            for (int ch = 0; ch < 4; ++ch) {
#pragma unroll
                for (int j = 0; j < NV; ++j) {
                    u16x8 cv = aux_read(ch, j);
#pragma unroll
                    for (int k = 0; k < 8; ++k) {
                        int i = 8*j + k;
                        hs[i>>2][i&3] += b2f(cv[k]);
                    }
                }
            }
            u16x8 sv[NV];
#pragma unroll
            for (int i = 0; i < NC; ++i) sv[i>>3][i&7] = f2b(hs[i>>2][i&3]);
            size_t zo = (size_t)gr * 1024 + gc0;
#pragma unroll
            for (int j = 0; j < NV; ++j) *(u16x8*)&zrb[zo + 8*j] = zv[j];
#pragma unroll
            for (int j = 0; j < NV; ++j) *(u16x8*)&zrb[zo + H + 8*j] = sv[j];
        } else {
            f32x4 rr[NC/4];
#pragma unroll
            for (int i = 0; i < NC; ++i) rr[i>>2][i&3] = sigm(va[i>>2][i&3]);
            const int cc = gc0 - H;
#pragma unroll
            for (int ch = 0; ch < 4; ++ch) {
#pragma unroll
                for (int j = 0; j < NV; ++j) {
                    u16x8 cv = aux_read(ch, j);
                    u16x8 ov;
#pragma unroll
                    for (int k = 0; k < 8; ++k) {
                        int i = 8*j + k;
                        ov[k] = f2b(rr[i>>2][i&3] * b2f(cv[k]));
                    }
                    *(u16x8*)&outb[(size_t)gr*2048 + ch*H + cc + 8*j] = ov;
                }
            }
        }
    } else { // EPI == 2
        size_t zo = (size_t)gr * 1024 + gc0;
        u16x8 zv[NV], sv[NV];
#pragma unroll
        for (int j = 0; j < NV; ++j) zv[j] = *(const u16x8*)&zrb[zo + 8*j];
#pragma unroll
        for (int j = 0; j < NV; ++j) sv[j] = *(const u16x8*)&zrb[zo + H + 8*j];
        f32x4 ov[NC/4]; u16x8 hv[NV];
#pragma unroll
        for (int i = 0; i < NC; ++i) {
            float hc = ftanh(va[i>>2][i&3]);
            float z  = b2f(zv[i>>3][i&7]);
            float v  = b2f(sv[i>>3][i&7]) * z + (1.f - z) * hc;
            ov[i>>2][i&3] = v; hv[i>>3][i&7] = f2b(v);
        }
        size_t o = (size_t)(outRow0 + gr) * H + gc0;
#pragma unroll
        for (int j = 0; j < NC/4; ++j) *(f32x4*)&outf[o + 4*j] = ov[j];
#pragma unroll
        for (int j = 0; j < NV; ++j) *(u16x8*)&outb[o + 8*j] = hv[j];
    }
}

// ---- EPI0 aux slice staging: 64 child rows x WC cols into per-wave LDS ----
template<int WC>
__device__ __forceinline__ void stage_aux(
    u16* wls, const u16* auxg, int lane)
{
    constexpr int UPW = WC / 8;          // 16B units per row
    constexpr int NIT = 64 * UPW / 64;   // instructions per wave
#pragma unroll
    for (int it = 0; it < NIT; ++it) {
        int row = (it * 64 + lane) / UPW;
        int sp  = (lane & (UPW - 1)) ^ ((row >> 2) & (UPW - 1));
        gload16(auxg + row * H + sp * 8, &wls[it * 512]);
    }
}

// ---------------- fp32 -> bf16 conversion (all tensors, one launch) --------
__global__ void cvt_all(const float* __restrict__ s0, u16* __restrict__ d0, int n0,
                        const float* __restrict__ s1, u16* __restrict__ d1, int n1,
                        const float* __restrict__ s2, u16* __restrict__ d2, int n2,
                        const float* __restrict__ s3, u16* __restrict__ d3, int n3)
{
    int i = blockIdx.x * blockDim.x + threadIdx.x;
    int st = gridDim.x * blockDim.x;
    int tot = n0 + n1 + n2 + n3;
    for (; i < tot; i += st) {
        const float* s; u16* d; int k = i;
        if (k < n0)      { s = s0; d = d0; }
        else { k -= n0;
        if (k < n1)      { s = s1; d = d1; }
        else { k -= n1;
        if (k < n2)      { s = s2; d = d2; }
        else { k -= n2;    s = s3; d = d3; } } }
        float4 v = ((const float4*)s)[k];
        ushort4 o;
        o.x = f2b(v.x); o.y = f2b(v.y); o.z = f2b(v.z); o.w = f2b(v.w);
        ((ushort4*)d)[k] = o;
    }
}

// ====== 512-thread 256xBN deep-pipeline kernel (big levels), 1 block/CU =====
// T3+T4 structure: NBUF=4 half-ring (K-half = 32), depth-3 prefetch, counted
// vmcnt (2L/L/0), ONE barrier per half, s_setprio(1) around the MFMA cluster.
// Ring safety: slot (h+3)&3 == slot (h-1)&3, whose readers all passed barrier
// h (lockstep) before any wave issues stage(h+3). Tile-h visibility: each
// wave's own vmwait<2L> drains its half-h loads BEFORE that same barrier.
// Swizzle per 32-K half identical to the audited zero-conflict pattern.
template<int EPI, int BN>
__global__ __launch_bounds__(512, 2) void gemm8p(
    const u16* __restrict__ A, int lda, int M, int K,
    const u16* __restrict__ Bm,
    const float* __restrict__ bias,
    float* __restrict__ outf,
    u16*  __restrict__ outb,
    u16*  __restrict__ zrb,
    const u16* __restrict__ auxb,
    int outRow0)
{
    constexpr int WAVES_M = (BN == 256) ? 2 : 4;
    constexpr int WAVES_N = 8 / WAVES_M;     // 4 or 2
    constexpr int WTM = 256 / WAVES_M;       // 128 or 64
    constexpr int MI  = WTM / 16;            // 8 or 4
    constexpr int NI  = 4;                   // wave covers 64 cols always
    constexpr int AH  = 256 * 32;            // u16 per A half-slot (16 KB)
    constexpr int BH  = BN * 32;             // u16 per B half-slot
    constexpr int LB  = BH / (8 * 512);      // B loads/thread/half: 2 or 1
    constexpr int L   = 2 + LB;              // loads/thread/half: 4 or 3

    __shared__ __align__(16) char smem[(4 * AH + 4 * BH) * 2]; // 128 or 96 KB
    u16* Asm = reinterpret_cast<u16*>(smem);
    u16* Bsm = reinterpret_cast<u16*>(smem) + 4 * AH;

    const int tid  = threadIdx.x;
    const int lane = tid & 63;
    const int wave = tid >> 6;
    const int wm = wave / WAVES_N;
    const int wn = wave % WAVES_N;

    int bx, by;
    {
        const int gx = gridDim.x, gy = gridDim.y;
        int p = blockIdx.y * gx + blockIdx.x;
        if ((gy & 7) == 0) {
            int xcd = p & 7, slot = p >> 3;
            bx = slot % gx;
            by = (slot / gx) * 8 + xcd;
        } else { bx = blockIdx.x; by = blockIdx.y; }
    }
    const int row0 = by * 256;
    const int col0 = bx * BN;

    auto stage = [&](int slot, int kt) {
#pragma unroll
        for (int j = 0; j < 2; ++j) {                 // A: 1024 units
            int e8  = j * 512 + tid;
            int row = e8 >> 2;
            int jc  = e8 & 3;
            int js  = jc ^ ((row >> 1) & 3);
            int ar = row0 + row; if (ar >= M) ar = M - 1;
            gload16(A + (size_t)ar * lda + kt + js * 8, &Asm[slot * AH + e8 * 8]);
        }
#pragma unroll
        for (int j = 0; j < LB; ++j) {                // B: BN*4 units
            int e8  = j * 512 + tid;
            int row = e8 >> 2;
            int jc  = e8 & 3;
            int js  = jc ^ ((row >> 1) & 3);
            gload16(Bm + (size_t)(col0 + row) * K + kt + js * 8,
                    &Bsm[slot * BH + e8 * 8]);
        }
    };

    f32x4 acc[MI][NI] = {};

    const int nh = K / 32;     // half-tiles (nh >= 3 for all call sites)
    stage(0, 0); stage(1, 32); stage(2, 64);

    const int rl = lane & 15;
    const int qq = lane >> 4;
    for (int h = 0; h < nh; ++h) {
        const int rem = nh - h;
        if (rem >= 3)      vmwait<2 * L>();
        else if (rem == 2) vmwait<L>();
        else               vmwait<0>();
        __builtin_amdgcn_s_barrier();
        asm volatile("" ::: "memory");
        if (h + 3 < nh) stage((h + 3) & 3, (h + 3) * 32);

        const u16* as = &Asm[(h & 3) * AH];
        const u16* bs = &Bsm[(h & 3) * BH];
        bf16x8 af[MI], bfr[NI];
#pragma unroll
        for (int mi = 0; mi < MI; ++mi) {
            int arow = wm * WTM + mi * 16 + rl;
            int u = qq ^ ((arow >> 1) & 3);
            af[mi] = *(const bf16x8*)&as[arow * 32 + u * 8];
        }
#pragma unroll
        for (int ni = 0; ni < NI; ++ni) {
            int brow = wn * 64 + ni * 16 + rl;
            int u = qq ^ ((brow >> 1) & 3);
            bfr[ni] = *(const bf16x8*)&bs[brow * 32 + u * 8];
        }
        __builtin_amdgcn_s_setprio(1);
#pragma unroll
        for (int mi = 0; mi < MI; ++mi)
#pragma unroll
            for (int ni = 0; ni < NI; ++ni)
                acc[mi][ni] = __builtin_amdgcn_mfma_f32_16x16x32_bf16(
                    af[mi], bfr[ni], acc[mi][ni], 0, 0, 0);
        __builtin_amdgcn_s_setprio(0);
    }

    // ---- epilogue: per-wave LDS transpose + (EPI0) coalesced aux restage ---
    float bcol[NI];
#pragma unroll
    for (int ni = 0; ni < NI; ++ni)
        bcol[ni] = bias[col0 + wn * 64 + ni * 16 + rl];

    __syncthreads();
    char* wreg = smem + wave * 8192;
    float* Csw = reinterpret_cast<float*>(wreg);
    u16*   wls = reinterpret_cast<u16*>(wreg);
    const int rq  = lane >> 4;
    const int rl2 = lane & 15;
#pragma unroll
    for (int mi = 0; mi < MI; ++mi) {
#pragma unroll
        for (int ni = 0; ni < NI; ++ni)
#pragma unroll
            for (int q = 0; q < 4; ++q)
                Csw[(rq*4 + q)*68 + ni*16 + rl2] = acc[mi][ni][q] + bcol[ni];
        asm volatile("s_waitcnt lgkmcnt(0)" ::: "memory");
        f32x4 va[4];
#pragma unroll
        for (int j = 0; j < 4; ++j)
            va[j] = *(const f32x4*)&Csw[rl2*68 + rq*16 + 4*j];
        if constexpr (EPI == 0) {
            asm volatile("s_waitcnt lgkmcnt(0)" ::: "memory");
            int c0 = ((col0 < H) ? col0 : col0 - H) + wn * 64;
            const u16* auxg = auxb + (size_t)(4*(row0 + wm*WTM + mi*16)) * H + c0;
            stage_aux<64>(wls, auxg, lane);
            vmwait<0>();
        }
        int gr  = row0 + wm*WTM + mi*16 + rl2;
        int gc0 = col0 + wn*64 + rq*16;
        if (gr < M)
            epi_vec<EPI, 16, 64>(va, gr, gc0, outf, outb, zrb, wls, rl2, rq*16, outRow0);
    }
}

// ============ 512-thread 128x128 kernel (mid levels): 8 waves, BK=32 =========
template<int EPI>
__global__ __launch_bounds__(512) void gemm512(
    const u16* __restrict__ A, int lda, int M, int K,
    const u16* __restrict__ Bm,
    const float* __restrict__ bias,
    float* __restrict__ outf,
    u16*  __restrict__ outb,
    u16*  __restrict__ zrb,
    const u16* __restrict__ auxb,
    int outRow0)
{
    __shared__ __align__(16) char smem[4*128*32*2 * 2];  // 65536 B
    u16 (*As)[128*32] = reinterpret_cast<u16(*)[128*32]>(smem);
    u16 (*Bs)[128*32] = reinterpret_cast<u16(*)[128*32]>(smem + 4*128*32*2);

    const int tid  = threadIdx.x;
    const int lane = tid & 63;
    const int wave = tid >> 6;
    const int wm = wave >> 2;
    const int wn = wave & 3;

    int bx, by;
    {
        const int gx = gridDim.x, gy = gridDim.y;
        int p = blockIdx.y * gx + blockIdx.x;
        if ((gy & 7) == 0) {
            int xcd = p & 7, slot = p >> 3;
            bx = slot % gx;
            by = (slot / gx) * 8 + xcd;
        } else { bx = blockIdx.x; by = blockIdx.y; }
    }
    const int row0 = by * 128;
    const int col0 = bx * 128;

    auto stage = [&](int b, int kt) {
        int e8  = tid;
        int row = e8 >> 2;
        int jc  = e8 & 3;
        int js  = jc ^ ((row >> 1) & 3);
        int ar = row0 + row; if (ar >= M) ar = M - 1;
        gload16(A + (size_t)ar * lda + kt + js * 8, &As[b][e8 * 8]);
        int br = col0 + row;
        gload16(Bm + (size_t)br * K + kt + js * 8, &Bs[b][e8 * 8]);
    };

    f32x4 acc[4][2] = {};

    const int nt = K / 32;
    stage(0, 0);
    stage(1, 32);

    const int rl = lane & 15;
    const int qq = lane >> 4;
    for (int t = 0; t < nt; ++t) {
        if (t + 2 < nt) {
            stage((t + 2) & 3, (t + 2) * 32);
            vmwait<4>();
        } else if (t + 2 == nt) {
            vmwait<2>();
        } else {
            vmwait<0>();
        }
        __builtin_amdgcn_s_barrier();
        asm volatile("" ::: "memory");

        const u16* as = As[t & 3];
        const u16* bs = Bs[t & 3];
        bf16x8 af[4], bfr[2];
#pragma unroll
        for (int mi = 0; mi < 4; ++mi) {
            int arow = wm * 64 + mi * 16 + rl;
            int u = qq ^ ((arow >> 1) & 3);
            af[mi] = *(const bf16x8*)&as[arow * 32 + u * 8];
        }
#pragma unroll
        for (int ni = 0; ni < 2; ++ni) {
            int brow = wn * 32 + ni * 16 + rl;
            int u = qq ^ ((brow >> 1) & 3);
            bfr[ni] = *(const bf16x8*)&bs[brow * 32 + u * 8];
        }
#pragma unroll
        for (int mi = 0; mi < 4; ++mi)
#pragma unroll
            for (int ni = 0; ni < 2; ++ni)
                acc[mi][ni] = __builtin_amdgcn_mfma_f32_16x16x32_bf16(
                    af[mi], bfr[ni], acc[mi][ni], 0, 0, 0);
    }

    // ---- epilogue ----
    float bcol[2];
#pragma unroll
    for (int ni = 0; ni < 2; ++ni)
        bcol[ni] = bias[col0 + wn * 32 + ni * 16 + rl];

    __syncthreads();
    char* wreg = smem + wave * 8192;
    float* Csw = reinterpret_cast<float*>(wreg);
    u16*   wls = reinterpret_cast<u16*>(wreg);
    const int rq  = lane >> 4;
    const int rl2 = lane & 15;
#pragma unroll
    for (int mi = 0; mi < 4; ++mi) {
#pragma unroll
        for (int ni = 0; ni < 2; ++ni)
#pragma unroll
            for (int q = 0; q < 4; ++q)
                Csw[(rq*4 + q)*36 + ni*16 + rl2] = acc[mi][ni][q] + bcol[ni];
        asm volatile("s_waitcnt lgkmcnt(0)" ::: "memory");
        f32x4 va[2];
#pragma unroll
        for (int j = 0; j < 2; ++j)
            va[j] = *(const f32x4*)&Csw[rl2*36 + rq*8 + 4*j];
        if constexpr (EPI == 0) {
            asm volatile("s_waitcnt lgkmcnt(0)" ::: "memory");
            int c0 = ((col0 < H) ? col0 : col0 - H) + wn * 32;
            const u16* auxg = auxb + (size_t)(4*(row0 + wm*64 + mi*16)) * H + c0;
            stage_aux<32>(wls, auxg, lane);
            vmwait<0>();
        }
        int gr  = row0 + wm*64 + mi*16 + rl2;
        int gc0 = col0 + wn*32 + rq*8;
        if (gr < M)
            epi_vec<EPI, 8, 32>(va, gr, gc0, outf, outb, zrb, wls, rl2, rq*8, outRow0);
    }
}

// ============ 256-thread 128x128 kernel (small levels) ======================
template<int EPI, int BK>
__global__ __launch_bounds__(256) void gemm_bt(
    const u16* __restrict__ A, int lda, int M, int K,
    const u16* __restrict__ Bm,
    const float* __restrict__ bias,
    float* __restrict__ outf,
    u16*  __restrict__ outb,
    u16*  __restrict__ zrb,
    const u16* __restrict__ auxb,
    int outRow0)
{
    constexpr int UPR = BK / 8;
    constexpr int L   = 2 * (128 * UPR) / 256;

    __shared__ __align__(16) char smem[4*128*BK*2 * 2];
    u16 (*As)[128*BK] = reinterpret_cast<u16(*)[128*BK]>(smem);
    u16 (*Bs)[128*BK] = reinterpret_cast<u16(*)[128*BK]>(smem + 4*128*BK*2);

    const int tid  = threadIdx.x;
    const int lane = tid & 63;
    const int wave = tid >> 6;
    const int wm = wave >> 1, wn = wave & 1;

    int bx, by;
    {
        const int gx = gridDim.x, gy = gridDim.y;
        int p = blockIdx.y * gx + blockIdx.x;
        if ((gy & 7) == 0) {
            int xcd = p & 7, slot = p >> 3;
            bx = slot % gx;
            by = (slot / gx) * 8 + xcd;
        } else { bx = blockIdx.x; by = blockIdx.y; }
    }
    const int row0 = by * 128;
    const int col0 = bx * 128;

    auto stage = [&](int b, int kt) {
#pragma unroll
        for (int j = 0; j < (128 * UPR) / 256; ++j) {
            int e8  = j * 256 + tid;
            int row = e8 / UPR;
            int jc  = e8 % UPR;
            int js  = (BK == 32) ? (jc ^ ((row >> 1) & 3)) : (jc ^ (row & 7));
            int ar = row0 + row; if (ar >= M) ar = M - 1;
            gload16(A + (size_t)ar * lda + kt + js * 8, &As[b][e8 * 8]);
            int br = col0 + row;
            gload16(Bm + (size_t)br * K + kt + js * 8, &Bs[b][e8 * 8]);
        }
    };

    f32x4 acc[4][4] = {};

    const int nt = K / BK;
    stage(0, 0);
    if (nt > 1) stage(1, BK);

    const int rl = lane & 15;
    const int qq = lane >> 4;
    for (int t = 0; t < nt; ++t) {
        if (t + 2 < nt) {
            stage((t + 2) & 3, (t + 2) * BK);
            vmwait<2 * L>();
        } else if (t + 2 == nt) {
            vmwait<L>();
        } else {
            vmwait<0>();
        }
        __builtin_amdgcn_s_barrier();
        asm volatile("" ::: "memory");

        const u16* as = As[t & 3];
        const u16* bs = Bs[t & 3];
#pragma unroll
        for (int ks = 0; ks < BK / 32; ++ks) {
            bf16x8 af[4], bfr[4];
#pragma unroll
            for (int mi = 0; mi < 4; ++mi) {
                int arow = wm * 64 + mi * 16 + rl;
                int u = (BK == 32) ? (qq ^ ((arow >> 1) & 3))
                                   : ((ks * 4 + qq) ^ (arow & 7));
                af[mi] = *(const bf16x8*)&as[arow * BK + u * 8];
            }
#pragma unroll
            for (int ni = 0; ni < 4; ++ni) {
                int brow = wn * 64 + ni * 16 + rl;
                int u = (BK == 32) ? (qq ^ ((brow >> 1) & 3))
                                   : ((ks * 4 + qq) ^ (brow & 7));
                bfr[ni] = *(const bf16x8*)&bs[brow * BK + u * 8];
            }
#pragma unroll
            for (int mi = 0; mi < 4; ++mi)
#pragma unroll
                for (int ni = 0; ni < 4; ++ni)
                    acc[mi][ni] = __builtin_amdgcn_mfma_f32_16x16x32_bf16(
                        af[mi], bfr[ni], acc[mi][ni], 0, 0, 0);
        }
    }

    // ---- epilogue ----
    float bcol[4];
#pragma unroll
    for (int ni = 0; ni < 4; ++ni)
        bcol[ni] = bias[col0 + wn * 64 + ni * 16 + rl];

    __syncthreads();
    char* wreg = smem + wave * 8192;
    float* Csw = reinterpret_cast<float*>(wreg);
    u16*   wls = reinterpret_cast<u16*>(wreg);
    const int rq  = lane >> 4;
    const int rl2 = lane & 15;
#pragma unroll
    for (int mi = 0; mi < 4; ++mi) {
#pragma unroll
        for (int ni = 0; ni < 4; ++ni)
#pragma unroll
            for (int q = 0; q < 4; ++q)
                Csw[(rq*4 + q)*68 + ni*16 + rl2] = acc[mi][ni][q] + bcol[ni];
        asm volatile("s_waitcnt lgkmcnt(0)" ::: "memory");
        f32x4 va[4];
#pragma unroll
        for (int j = 0; j < 4; ++j)
            va[j] = *(const f32x4*)&Csw[rl2*68 + rq*16 + 4*j];
        if constexpr (EPI == 0) {
            asm volatile("s_waitcnt lgkmcnt(0)" ::: "memory");
            int c0 = ((col0 < H) ? col0 : col0 - H) + wn * 64;
            const u16* auxg = auxb + (size_t)(4*(row0 + wm*64 + mi*16)) * H + c0;
            stage_aux<64>(wls, auxg, lane);
            vmwait<0>();
        }
        int gr  = row0 + wm*64 + mi*16 + rl2;
        int gc0 = col0 + wn*64 + rq*16;
        if (gr < M)
            epi_vec<EPI, 16, 64>(va, gr, gc0, outf, outb, zrb, wls, rl2, rq*16, outRow0);
    }
}

extern "C" void kernel_launch(void* const* d_in, const int* in_sizes, int n_in,
                              void* d_out, int out_size, void* d_ws, size_t ws_size,
                              hipStream_t stream) {
    const float* x     = (const float*)d_in[0];
    const float* Ww    = (const float*)d_in[1];
    const float* Wb    = (const float*)d_in[2];
    const float* Uzr_w = (const float*)d_in[3];
    const float* Uzr_b = (const float*)d_in[4];
    const float* Uh_w  = (const float*)d_in[5];
    const float* Uh_b  = (const float*)d_in[6];
    float* out = (float*)d_out;

    char* ws = (char*)d_ws;
    size_t off = 0;
    u16* hb   = (u16*)(ws + off); off += (size_t)NNODES * H * 2;       // 89.5 MB
    u16* zr   = (u16*)(ws + off); off += (size_t)16384 * 1024 * 2;     // 32 MB
    u16* rhxb = (u16*)(ws + off); off += (size_t)16384 * 2048 * 2;     // 64 MB
    u16* Wwb  = (u16*)(ws + off); off += (size_t)512 * 512 * 2;
    u16* Uzrb = (u16*)(ws + off); off += (size_t)1024 * 2048 * 2;
    u16* Uhb  = (u16*)(ws + off); off += (size_t)512 * 2048 * 2;

    // 1) convert weights + leaf x to bf16 (single launch)
    cvt_all<<<dim3(8192), 256, 0, stream>>>(
        Ww, Wwb, 512 * 512 / 4,
        Uzr_w, Uzrb, 1024 * 2048 / 4,
        Uh_w, Uhb, 512 * 2048 / 4,
        x + (size_t)LEAF0 * H, rhxb, NLEAF * H / 4);

    // 2) leaf GEMM: h = tanh(x @ Ww^T + Wb) — deep-pipeline 256x128
    gemm8p<1, 128><<<dim3(H / 128, NLEAF / 256), 512, 0, stream>>>(
        rhxb, H, NLEAF, H, Wwb, Wb, out, hb, nullptr, nullptr, LEAF0);

    // 3) levels 7..0
    static const int pow4[9] = {1, 4, 16, 64, 256, 1024, 4096, 16384, 65536};
    int starts[10]; starts[0] = 0;
    for (int l = 0; l < 9; ++l) starts[l + 1] = starts[l] + pow4[l];

    for (int l = 7; l >= 0; --l) {
        int s = starts[l], m = pow4[l];
        int cs = 4 * s + 1;  // children rows are contiguous: [cs, cs+4m)
        if (m >= 16384) {
            // L7: deep-pipeline kernels (Uzr 256x256 grid 4x64; Uh 256x128 4x64)
            gemm8p<0, 256><<<dim3(1024 / 256, m / 256), 512, 0, stream>>>(
                hb + (size_t)cs * H, 2048, m, 2048, Uzrb, Uzr_b,
                nullptr, rhxb, zr, hb + (size_t)cs * H, 0);
            gemm8p<2, 128><<<dim3(H / 128, m / 256), 512, 0, stream>>>(
                rhxb, 2048, m, 2048, Uhb, Uh_b,
                out, hb, zr, nullptr, s);
        } else if (m >= 4096) {
            int gm = (m + 127) / 128;
            gemm512<0><<<dim3(1024 / 128, gm), 512, 0, stream>>>(
                hb + (size_t)cs * H, 2048, m, 2048, Uzrb, Uzr_b,
                nullptr, rhxb, zr, hb + (size_t)cs * H, 0);
            gemm512<2><<<dim3(H / 128, gm), 512, 0, stream>>>(
                rhxb, 2048, m, 2048, Uhb, Uh_b,
                out, hb, zr, nullptr, s);
        } else {
            int gm = (m + 127) / 128;
            gemm_bt<0, 64><<<dim3(1024 / 128, gm), 256, 0, stream>>>(
                hb + (size_t)cs * H, 2048, m, 2048, Uzrb, Uzr_b,
                nullptr, rhxb, zr, hb + (size_t)cs * H, 0);
            gemm_bt<2, 64><<<dim3(H / 128, gm), 256, 0, stream>>>(
                rhxb, 2048, m, 2048, Uhb, Uh_b,
                out, hb, zr, nullptr, s);
        }
    }
}